// Round 15
// baseline (166.379 us; speedup 1.0000x reference)
//
#include <hip/hip_runtime.h>
#include <stdint.h>

// Problem constants
#define BATCH   8
#define NMASK_  1024
#define SEQ     1025          // NMASK + 1 (CLS prepended)
#define NPAD    1056          // SEQ padded to multiple of 32
#define DIM     768
#define HEADS   12
#define HD      64
#define BHN     (BATCH*HEADS) // 96
#define MROWS   (BATCH*SEQ)   // 8200
#define K3      (3*DIM)       // 2304

typedef unsigned short u16;
typedef __attribute__((ext_vector_type(8))) short s8v;   // 8 bf16 (A/B frag)
typedef __attribute__((ext_vector_type(4))) float f4v;   // C/D frag
typedef __attribute__((ext_vector_type(4))) unsigned short u16x4;

__device__ __forceinline__ u16 rne_bf16(float f) {
  unsigned u = __float_as_uint(f);
  u += 0x7fffu + ((u >> 16) & 1u);      // round-to-nearest-even
  return (u16)(u >> 16);
}
__device__ __forceinline__ float bf2f(u16 u) {
  return __uint_as_float(((unsigned)u) << 16);
}

// async global->LDS, 16B per lane; LDS dest = wave-uniform base + lane*16
__device__ __forceinline__ void gld16(const u16* g, u16* l) {
  __builtin_amdgcn_global_load_lds(
      (const __attribute__((address_space(1))) void*)g,
      (__attribute__((address_space(3))) void*)l, 16, 0, 0);
}

// raw barrier with compiler memory fences (no vmcnt(0) drain inserted)
__device__ __forceinline__ void barrier_() {
  asm volatile("" ::: "memory");
  __builtin_amdgcn_s_barrier();
  asm volatile("" ::: "memory");
}

// ---------------- merged prep: lens (blocks 0..7) + VT pad zero (rest) ------
__global__ __launch_bounds__(256) void k_prep(const int* __restrict__ mask,
                                              int* __restrict__ lens,
                                              u16* __restrict__ VT) {
  int bid = blockIdx.x, t = threadIdx.x;
  if (bid < BATCH) {
    int b = bid, s = 0;
    for (int j = t; j < NMASK_; j += 256) s += (mask[b * NMASK_ + j] != 0) ? 1 : 0;
    __shared__ int red[256];
    red[t] = s; __syncthreads();
    for (int st = 128; st > 0; st >>= 1) { if (t < st) red[t] += red[t + st]; __syncthreads(); }
    if (t == 0) lens[b] = red[0] + 1;
  } else {
    int idx = (bid - BATCH) * 256 + t;
    const int PADW = NPAD - SEQ; // 31
    if (idx >= BHN * HD * PADW) return;
    int c = idx % PADW, rd = idx / PADW; // rd = bh*HD + d
    VT[(size_t)rd * NPAD + SEQ + c] = 0;
  }
}

// ---------------- x -> bf16 ---------------------------------------------------
__global__ __launch_bounds__(256) void k_cvt_x(const float* __restrict__ x,
                                               u16* __restrict__ xb, int n4) {
  int i = blockIdx.x * 256 + threadIdx.x;
  if (i >= n4) return;
  float4 v = ((const float4*)x)[i];
  u16x4 o;
  o[0] = rne_bf16(v.x); o[1] = rne_bf16(v.y); o[2] = rne_bf16(v.z); o[3] = rne_bf16(v.w);
  *(u16x4*)&xb[i * 4] = o;
}

// ---------------- merged transpose+convert for both weight matrices ----------
// x-tiles [0, K3/32) -> w_qkv (C=K3); [K3/32, K3/32+DIM/32) -> w_proj (C=DIM)
__global__ __launch_bounds__(256) void k_wT2(const float* __restrict__ wq,
                                             const float* __restrict__ wp,
                                             u16* __restrict__ wqT,
                                             u16* __restrict__ wpT) {
  __shared__ float tile[32][33];
  const bool isq = blockIdx.x < (K3 / 32);
  const float* w = isq ? wq : wp;
  u16* wT = isq ? wqT : wpT;
  const int C = isq ? K3 : DIM;
  int c0 = (isq ? blockIdx.x : blockIdx.x - K3 / 32) * 32, r0 = blockIdx.y * 32;
  int tx = threadIdx.x & 31, ty = threadIdx.x >> 5;   // 32 x 8
  #pragma unroll
  for (int i = 0; i < 32; i += 8) tile[ty + i][tx] = w[(size_t)(r0 + ty + i) * C + c0 + tx];
  __syncthreads();
  #pragma unroll
  for (int i = 0; i < 32; i += 8)
    wT[(size_t)(c0 + ty + i) * DIM + r0 + tx] = rne_bf16(tile[tx][ty + i]);
}

// ---------------- 128x128 MFMA mainloop (BK=32, dbuf + counted vmcnt) --------
__device__ __forceinline__ void gemm_ml128(const u16* __restrict__ A,
                                           const u16* __restrict__ Bt,
                                           int M, int m0, int n0,
                                           f4v acc[4][4], u16* smem) {
  const int t = threadIdx.x;
  const int w = t >> 6, l = t & 63, lg = l >> 4, lr = l & 15;
  const int wr = w >> 1, wc = w & 1;

  int rA0 = m0 + (t >> 2);       if (rA0 >= M) rA0 = M - 1;   // clamp M edge
  int rA1 = m0 + (t >> 2) + 64;  if (rA1 >= M) rA1 = M - 1;
  const u16* sA0 = A  + (size_t)rA0 * DIM + (t & 3) * 8;
  const u16* sA1 = A  + (size_t)rA1 * DIM + (t & 3) * 8;
  const u16* sB0 = Bt + (size_t)(n0 + (t >> 2)) * DIM + (t & 3) * 8;
  const u16* sB1 = Bt + (size_t)(n0 + (t >> 2) + 64) * DIM + (t & 3) * 8;
  const int dO0 = w * 512, dO1 = 2048 + w * 512;   // wave-uniform (u16 idx)

  #pragma unroll
  for (int fm = 0; fm < 4; fm++)
    #pragma unroll
    for (int fn = 0; fn < 4; fn++) { f4v z = {0.f, 0.f, 0.f, 0.f}; acc[fm][fn] = z; }

  // prologue: tile 0 -> buf 0 (4 loads in flight)
  gld16(sA0, &smem[dO0]);        gld16(sA1, &smem[dO1]);
  gld16(sB0, &smem[8192 + dO0]); gld16(sB1, &smem[8192 + dO1]);

  const int NT = DIM / 32;   // 24
  for (int kt = 0; kt < NT; ++kt) {
    const int p = kt & 1;
    if (kt + 1 < NT) {
      const int ka = (kt + 1) * 32;
      const int nb = (p ^ 1) * 4096;
      gld16(sA0 + ka, &smem[nb + dO0]);        gld16(sA1 + ka, &smem[nb + dO1]);
      gld16(sB0 + ka, &smem[8192 + nb + dO0]); gld16(sB1 + ka, &smem[8192 + nb + dO1]);
      asm volatile("s_waitcnt vmcnt(4)" ::: "memory");  // tile kt landed; kt+1 flies
    } else {
      asm volatile("s_waitcnt vmcnt(0)" ::: "memory");  // final drain
    }
    __builtin_amdgcn_sched_barrier(0);
    barrier_();                          // all waves' tile-kt data visible
    const u16* lA = &smem[p * 4096];
    const u16* lB = &smem[8192 + p * 4096];
    s8v a[4], bb[4];
    #pragma unroll
    for (int fm = 0; fm < 4; fm++) a[fm] = *(const s8v*)&lA[(wr * 64 + fm * 16 + lr) * 32 + lg * 8];
    #pragma unroll
    for (int fn = 0; fn < 4; fn++) bb[fn] = *(const s8v*)&lB[(wc * 64 + fn * 16 + lr) * 32 + lg * 8];
    #pragma unroll
    for (int fm = 0; fm < 4; fm++)
      #pragma unroll
      for (int fn = 0; fn < 4; fn++)
        acc[fm][fn] = __builtin_amdgcn_mfma_f32_16x16x32_bf16(a[fm], bb[fn], acc[fm][fn], 0, 0, 0);
    barrier_();                          // buf p reads closed before kt+2 writes it
  }
}

// ---------------- QKV GEMM + coalesced LDS-transposed scatter epilogue -------
// Q pre-scaled by 0.125*log2(e) so attention can use exp2 (1 VALU op).
__global__ __launch_bounds__(256) void k_gemm_qkv(const u16* __restrict__ xb,
                                                  const u16* __restrict__ wqkvT,
                                                  const float* __restrict__ bqkv,
                                                  const int* __restrict__ lens,
                                                  u16* __restrict__ Q,
                                                  u16* __restrict__ Kb,
                                                  u16* __restrict__ VT) {
  __shared__ alignas(16) u16 smem[16384];   // 32 KB: mainloop; then C-tile
  int m0 = blockIdx.x * 128, n0 = blockIdx.y * 128;
  const int which = n0 / DIM;               // 0=q 1=k 2=v (uniform per block)
  if (which < 2) {                          // Q or K tile: skip if all rows invalid
    int b0 = m0 / SEQ, off = m0 - b0 * SEQ;
    bool spans = (m0 + 127) >= (b0 + 1) * SEQ;
    if (!spans && off >= lens[b0]) return;
  }
  f4v acc[4][4];
  gemm_ml128(xb, wqkvT, MROWS, m0, n0, acc, smem);
  const int t = threadIdx.x;
  const int w = t >> 6, l = t & 63, lg = l >> 4, lr = l & 15;
  const int wr = w >> 1, wc = w & 1;
  const int hbase = (n0 - which * DIM) >> 6;
  const float qs = (which == 0) ? 0.18033688f : 1.0f;   // 0.125 * log2(e)

  __syncthreads();                          // mainloop LDS dead
  #pragma unroll
  for (int fn = 0; fn < 4; fn++) {
    int col = wc * 64 + fn * 16 + lr;
    float bias = bqkv[n0 + col];
    #pragma unroll
    for (int fm = 0; fm < 4; fm++)
      #pragma unroll
      for (int r = 0; r < 4; r++) {
        int row = wr * 64 + fm * 16 + lg * 4 + r;
        smem[row * 128 + col] = rne_bf16((acc[fm][fn][r] + bias) * qs);
      }
  }
  __syncthreads();

  if (which < 2) {
    // Q/K: [n][d] layout -> 16B chunks along d; wave covers 4 rows x 256 B
    u16* dst = (which == 0) ? Q : Kb;
    #pragma unroll
    for (int p = 0; p < 8; p++) {
      int c = p * 256 + t;                  // 2048 chunks
      int row = c >> 4, col = (c & 15) * 8;
      int gm = m0 + row;
      if (gm >= MROWS) continue;
      int b = gm / SEQ, n = gm - b * SEQ;
      int head = hbase + (col >> 6), d = col & 63;
      *(s8v*)&dst[((size_t)(b * HEADS + head) * NPAD + n) * HD + d] =
          *(const s8v*)&smem[row * 128 + col];
    }
  } else {
    // V: transposed [d][n] -> 16B chunks along n (8 rows gathered per chunk)
    #pragma unroll
    for (int p = 0; p < 8; p++) {
      int c = p * 256 + t;
      int d = c & 127, nb = c >> 7;         // 128 cols x 16 row-blocks
      int gm0 = m0 + nb * 8;
      if (gm0 >= MROWS) continue;
      int head = hbase + (d >> 6), dl = d & 63;
      int b0 = gm0 / SEQ;
      if (gm0 + 7 < MROWS && (gm0 + 7) < (b0 + 1) * SEQ) {     // run stays in batch
        s8v v;
        #pragma unroll
        for (int e = 0; e < 8; e++) v[e] = (short)smem[(nb * 8 + e) * 128 + d];
        int n = gm0 - b0 * SEQ;
        *(s8v*)&VT[((size_t)(b0 * HEADS + head) * HD + dl) * NPAD + n] = v;
      } else {                              // crosses batch boundary / M edge
        for (int e = 0; e < 8; e++) {
          int gm = gm0 + e;
          if (gm >= MROWS) break;
          int b = gm / SEQ, n = gm - b * SEQ;
          VT[((size_t)(b * HEADS + head) * HD + dl) * NPAD + n] = smem[(nb * 8 + e) * 128 + d];
        }
      }
    }
  }
}

// ---------------- per-(b,h) mean of V over all SEQ rows ----------------------
__global__ __launch_bounds__(256) void k_vmean(const u16* __restrict__ VT,
                                               float* __restrict__ vmean) {
  int bh = blockIdx.x, t = threadIdx.x;
  int d = t >> 2, part = t & 3;
  const u16* row = VT + (size_t)(bh * HD + d) * NPAD;
  float s = 0.f;
  for (int jc = part * 264; jc < part * 264 + 264; jc += 8) {
    if (jc + 8 <= SEQ) {
      s8v v = *(const s8v*)&row[jc];
      #pragma unroll
      for (int e = 0; e < 8; e++) s += bf2f((u16)v[e]);
    } else {
      for (int e = 0; e < 8; e++) if (jc + e < SEQ) s += bf2f(row[jc + e]);
    }
  }
  __shared__ float red[256];
  red[t] = s; __syncthreads();
  if (part == 0)
    vmean[bh * HD + d] = (red[t] + red[t + 1] + red[t + 2] + red[t + 3]) * (1.0f / (float)SEQ);
}

// ---------------- vproj[b*DIM+n] = vmean[b] . wprojT[n] + bproj[n] -----------
// wave-per-output GEMV: 6144 outputs, 4 waves/block, 1536 blocks.
__global__ __launch_bounds__(256) void k_vproj(const float* __restrict__ vmean,
                                               const u16* __restrict__ wprojT,
                                               const float* __restrict__ bproj,
                                               float* __restrict__ vproj) {
  int gid = blockIdx.x * 4 + (threadIdx.x >> 6);   // output index
  if (gid >= BATCH * DIM) return;
  int b = gid / DIM, n = gid - b * DIM;
  int l = threadIdx.x & 63;
  const u16* wr = wprojT + (size_t)n * DIM;
  const float* vm = vmean + b * DIM;
  float s = 0.f;
  #pragma unroll
  for (int i = 0; i < DIM / 64; ++i)               // 12 coalesced strided MACs
    s += vm[l + i * 64] * bf2f(wr[l + i * 64]);
  #pragma unroll
  for (int off = 32; off >= 1; off >>= 1) s += __shfl_xor(s, off);
  if (l == 0) vproj[gid] = s + bproj[n];
}

// ---------------- flash attention over the valid prefix ----------------------
// grid (96 bh, 17 qtile) — bh-major => all q-tiles of a bh share an XCD.
// 4 waves x 16 Q-rows (QBLK=64); KVBLK=64; T14 reg-staged issue-early.
// NO-MAX + EXP2 softmax: Q pre-scaled by 0.125*log2(e) => P=exp2(s) (single
// v_exp_f32); masked -> exp2(-1e30)=+0. Softmax scale-invariant.
__global__ __launch_bounds__(256) void k_attn(const u16* __restrict__ Q,
                                              const u16* __restrict__ Kb,
                                              const u16* __restrict__ VT,
                                              const int* __restrict__ lens,
                                              u16* __restrict__ aout) {
  int bh = blockIdx.x; int b = bh / HEADS, h = bh - b * HEADS;
  int Lp1 = lens[b];
  int q0 = blockIdx.y * 64;
  if (q0 >= Lp1) return;                      // invalid rows: vproj path
  __shared__ alignas(16) u16 Kt[64 * 64];     // [j][d], XOR-swizzled 16B granules
  __shared__ alignas(16) u16 Vt[64 * 64];     // [d][k], XOR-swizzled
  __shared__ alignas(16) u16 Pt[4][16 * 72];  // per-wave P tile, 144B stride
  const int t = threadIdx.x, w = t >> 6, l = t & 63, lg = l >> 4, lr = l & 15;
  const u16* Qbh = Q  + (size_t)bh * NPAD * HD;
  const u16* Kbh = Kb + (size_t)bh * NPAD * HD;
  const u16* Vbh = VT + (size_t)bh * HD * NPAD;

  int qi = q0 + w * 16 + lr;                  // A-frag row (l&15)
  s8v qf[2];
  qf[0] = *(const s8v*)&Qbh[(size_t)qi * HD +      lg * 8];
  qf[1] = *(const s8v*)&Qbh[(size_t)qi * HD + 32 + lg * 8];

  f4v o[4];
  #pragma unroll
  for (int fd = 0; fd < 4; fd++) { f4v z = {0.f, 0.f, 0.f, 0.f}; o[fd] = z; }
  float ssacc[4];                             // per-lane partial row sums
  #pragma unroll
  for (int r = 0; r < 4; r++) ssacc[r] = 0.f;

  // T14 staging: per-thread row js (0..63), chunk pair cs/cs+4
  const int js = t >> 2, cs = t & 3;
  const u16* kSrc = Kbh + (size_t)js * HD   + cs * 8;
  const u16* vSrc = Vbh + (size_t)js * NPAD + cs * 8;
  const int kDst0 = js * 64 + ((cs       ^ (js & 7)) * 8);
  const int kDst1 = js * 64 + (((cs + 4) ^ (js & 7)) * 8);
  s8v kr0, kr1, vr0, vr1;
  kr0 = *(const s8v*)(kSrc);        kr1 = *(const s8v*)(kSrc + 32);   // tile 0
  vr0 = *(const s8v*)(vSrc);        vr1 = *(const s8v*)(vSrc + 32);

  for (int j0 = 0; j0 < Lp1; j0 += 64) {
    __syncthreads();                          // Kt/Vt free (prev tile consumed)
    *(s8v*)&Kt[kDst0] = kr0;  *(s8v*)&Kt[kDst1] = kr1;
    *(s8v*)&Vt[kDst0] = vr0;  *(s8v*)&Vt[kDst1] = vr1;
    if (j0 + 64 < Lp1) {                      // issue next loads: fly over compute
      kr0 = *(const s8v*)(kSrc + (size_t)(j0 + 64) * HD);
      kr1 = *(const s8v*)(kSrc + (size_t)(j0 + 64) * HD + 32);
      vr0 = *(const s8v*)(vSrc + (j0 + 64));
      vr1 = *(const s8v*)(vSrc + (j0 + 64) + 32);
    }
    __syncthreads();

    // S = Q K^T  (four 16-col j-frags, k = 64 in two steps)
    f4v sf[4];
    #pragma unroll
    for (int jf = 0; jf < 4; jf++) { f4v z = {0.f,0.f,0.f,0.f}; sf[jf] = z; }
    __builtin_amdgcn_s_setprio(1);
    #pragma unroll
    for (int jf = 0; jf < 4; jf++) {
      int j = jf * 16 + lr;                    // B-frag col (l&15)
      #pragma unroll
      for (int kf = 0; kf < 2; kf++) {
        s8v kfr = *(const s8v*)&Kt[j * 64 + (((kf * 4 + lg) ^ (j & 7)) * 8)];
        sf[jf] = __builtin_amdgcn_mfma_f32_16x16x32_bf16(qf[kf], kfr, sf[jf], 0, 0, 0);
      }
    }
    __builtin_amdgcn_s_setprio(0);

    u16* P = &Pt[w][0];
    if (j0 + 64 <= Lp1) {                     // full tile: exp2 directly
      #pragma unroll
      for (int r = 0; r < 4; r++) {
        float e0 = exp2f(sf[0][r]);
        float e1 = exp2f(sf[1][r]);
        float e2 = exp2f(sf[2][r]);
        float e3 = exp2f(sf[3][r]);
        int prow = (lg * 4 + r) * 72;
        P[prow +      lr] = rne_bf16(e0);
        P[prow + 16 + lr] = rne_bf16(e1);
        P[prow + 32 + lr] = rne_bf16(e2);
        P[prow + 48 + lr] = rne_bf16(e3);
        ssacc[r] += (e0 + e1) + (e2 + e3);
      }
    } else {                                  // tail tile: mask invalid cols
      bool ok[4];
      #pragma unroll
      for (int jf = 0; jf < 4; jf++) ok[jf] = (j0 + jf * 16 + lr) < Lp1;
      #pragma unroll
      for (int r = 0; r < 4; r++) {
        float e0 = exp2f(ok[0] ? sf[0][r] : -1e30f);  // masked/NaN -> exactly 0
        float e1 = exp2f(ok[1] ? sf[1][r] : -1e30f);
        float e2 = exp2f(ok[2] ? sf[2][r] : -1e30f);
        float e3 = exp2f(ok[3] ? sf[3][r] : -1e30f);
        int prow = (lg * 4 + r) * 72;
        P[prow +      lr] = rne_bf16(e0);
        P[prow + 16 + lr] = rne_bf16(e1);
        P[prow + 32 + lr] = rne_bf16(e2);
        P[prow + 48 + lr] = rne_bf16(e3);
        ssacc[r] += (e0 + e1) + (e2 + e3);
      }
    }
    asm volatile("s_waitcnt lgkmcnt(0)" ::: "memory");   // wave-local LDS RAW
    s8v pa[2];
    pa[0] = *(const s8v*)&P[lr * 72 +      lg * 8];
    pa[1] = *(const s8v*)&P[lr * 72 + 32 + lg * 8];
    __builtin_amdgcn_s_setprio(1);
    #pragma unroll
    for (int fd = 0; fd < 4; fd++) {
      int dv = fd * 16 + lr;
      #pragma unroll
      for (int kf = 0; kf < 2; kf++) {
        s8v vb = *(const s8v*)&Vt[dv * 64 + (((kf * 4 + lg) ^ (dv & 7)) * 8)];
        o[fd] = __builtin_amdgcn_mfma_f32_16x16x32_bf16(pa[kf], vb, o[fd], 0, 0, 0);
      }
    }
    __builtin_amdgcn_s_setprio(0);
  }

  float inv[4];
  #pragma unroll
  for (int r = 0; r < 4; r++) {               // single end reduce over 16 lanes
    float rs = ssacc[r];
    rs += __shfl_xor(rs, 1); rs += __shfl_xor(rs, 2);
    rs += __shfl_xor(rs, 4); rs += __shfl_xor(rs, 8);
    inv[r] = 1.0f / rs;
  }
  #pragma unroll
  for (int fd = 0; fd < 4; fd++)
    #pragma unroll
    for (int r = 0; r < 4; r++) {
      int i = q0 + w * 16 + lg * 4 + r;
      if (i < Lp1)
        aout[(size_t)(b * SEQ + i) * DIM + h * HD + fd * 16 + lr] = rne_bf16(o[fd][r] * inv[r]);
    }
}

// ---------------- output projection + bias + folded broadcast ----------------
// Fully-invalid row tiles: skip mainloop, write vproj rows directly (was
// k_bcast). Spans tiles: per-row select acc vs vproj in the epilogue.
__global__ __launch_bounds__(256) void k_gemm_proj(const u16* __restrict__ aout,
                                                   const u16* __restrict__ wprojT,
                                                   const float* __restrict__ bproj,
                                                   const int* __restrict__ lens,
                                                   const float* __restrict__ vproj,
                                                   float* __restrict__ out) {
  __shared__ alignas(16) u16 smem[16384];
  int m0 = blockIdx.x * 128, n0 = blockIdx.y * 128;
  int b0 = m0 / SEQ, off = m0 - b0 * SEQ;
  bool spans = (m0 + 127) >= (b0 + 1) * SEQ;
  if (!spans && off >= lens[b0]) {
    // broadcast path: all 128 rows invalid -> out rows = vproj[b0]
    float4 v = ((const float4*)&vproj[b0 * DIM + n0])[threadIdx.x & 31];
    for (int r = threadIdx.x >> 5; r < 128; r += 8) {
      int gm = m0 + r;
      if (gm < MROWS)
        ((float4*)&out[(size_t)gm * DIM + n0])[threadIdx.x & 31] = v;
    }
    return;
  }
  f4v acc[4][4];
  gemm_ml128(aout, wprojT, MROWS, m0, n0, acc, smem);
  const int t = threadIdx.x;
  const int w = t >> 6, l = t & 63, lg = l >> 4, lr = l & 15;
  const int wr = w >> 1, wc = w & 1;
  #pragma unroll
  for (int fn = 0; fn < 4; fn++) {
    int gc = n0 + wc * 64 + fn * 16 + lr;
    float bias = bproj[gc];
    #pragma unroll
    for (int fm = 0; fm < 4; fm++)
      #pragma unroll
      for (int r = 0; r < 4; r++) {
        int gm = m0 + wr * 64 + fm * 16 + lg * 4 + r;
        if (gm >= MROWS) continue;
        int b = gm / SEQ, n = gm - b * SEQ;
        float v = (n < lens[b]) ? (acc[fm][fn][r] + bias) : vproj[b * DIM + gc];
        out[(size_t)gm * DIM + gc] = v;
      }
  }
}

// ---------------- launch ------------------------------------------------------
extern "C" void kernel_launch(void* const* d_in, const int* in_sizes, int n_in,
                              void* d_out, int out_size, void* d_ws, size_t ws_size,
                              hipStream_t stream) {
  const float* x      = (const float*)d_in[0];
  const int*   mask   = (const int*)  d_in[1];
  const float* w_qkv  = (const float*)d_in[2];
  const float* b_qkv  = (const float*)d_in[3];
  const float* w_proj = (const float*)d_in[4];
  const float* b_proj = (const float*)d_in[5];
  float* out = (float*)d_out;

  // workspace layout (bf16 elems); aout aliases xb (xb dead after qkv GEMM)
  u16* xb     = (u16*)d_ws;                          // 8200*768
  u16* wqkvT  = xb    + (size_t)MROWS * DIM;         // 2304*768
  u16* wprojT = wqkvT + (size_t)K3 * DIM;            // 768*768
  u16* Q      = wprojT + (size_t)DIM * DIM;          // 96*1056*64
  u16* Kb     = Q     + (size_t)BHN * NPAD * HD;
  u16* VT     = Kb    + (size_t)BHN * NPAD * HD;
  float* vmean = (float*)(VT + (size_t)BHN * NPAD * HD);
  int* lens    = (int*)(vmean + BHN * HD);
  float* vproj = (float*)(lens + 256);               // 8*768 f32
  u16* aout   = xb;                                  // alias: safe, stream-ordered
  // total ~56.3 MB of d_ws

  const int ZBLK = (BHN * HD * (NPAD - SEQ) + 255) / 256;   // 744
  k_prep <<<dim3(BATCH + ZBLK), dim3(256), 0, stream>>>(mask, lens, VT);
  k_cvt_x<<<dim3((MROWS * DIM / 4 + 255) / 256), dim3(256), 0, stream>>>(x, xb, MROWS * DIM / 4);
  k_wT2  <<<dim3(K3 / 32 + DIM / 32, DIM / 32), dim3(256), 0, stream>>>(w_qkv, w_proj, wqkvT, wprojT);
  k_gemm_qkv<<<dim3((MROWS + 127) / 128, K3 / 128), dim3(256), 0, stream>>>(xb, wqkvT, b_qkv, lens, Q, Kb, VT);
  k_vmean<<<dim3(BHN), dim3(256), 0, stream>>>(VT, vmean);
  k_vproj<<<dim3((BATCH * DIM + 3) / 4), dim3(256), 0, stream>>>(vmean, wprojT, b_proj, vproj);
  k_attn <<<dim3(BHN, (SEQ + 63) / 64), dim3(256), 0, stream>>>(Q, Kb, VT, lens, aout);
  k_gemm_proj<<<dim3((MROWS + 127) / 128, DIM / 128), dim3(256), 0, stream>>>(aout, wprojT, b_proj, lens, vproj, out);
}

// Round 16
// 164.791 us; speedup vs baseline: 1.0096x; 1.0096x over previous
//
#include <hip/hip_runtime.h>
#include <stdint.h>

// Problem constants
#define BATCH   8
#define NMASK_  1024
#define SEQ     1025          // NMASK + 1 (CLS prepended)
#define NPAD    1056          // SEQ padded to multiple of 32
#define DIM     768
#define HEADS   12
#define HD      64
#define BHN     (BATCH*HEADS) // 96
#define MROWS   (BATCH*SEQ)   // 8200
#define K3      (3*DIM)       // 2304

typedef unsigned short u16;
typedef __attribute__((ext_vector_type(8))) short s8v;   // 8 bf16 (A/B frag)
typedef __attribute__((ext_vector_type(4))) float f4v;   // C/D frag
typedef __attribute__((ext_vector_type(4))) unsigned short u16x4;

__device__ __forceinline__ u16 rne_bf16(float f) {
  unsigned u = __float_as_uint(f);
  u += 0x7fffu + ((u >> 16) & 1u);      // round-to-nearest-even
  return (u16)(u >> 16);
}
__device__ __forceinline__ float bf2f(u16 u) {
  return __uint_as_float(((unsigned)u) << 16);
}

// async global->LDS, 16B per lane; LDS dest = wave-uniform base + lane*16
__device__ __forceinline__ void gld16(const u16* g, u16* l) {
  __builtin_amdgcn_global_load_lds(
      (const __attribute__((address_space(1))) void*)g,
      (__attribute__((address_space(3))) void*)l, 16, 0, 0);
}

// raw barrier with compiler memory fences (no vmcnt(0) drain inserted)
__device__ __forceinline__ void barrier_() {
  asm volatile("" ::: "memory");
  __builtin_amdgcn_s_barrier();
  asm volatile("" ::: "memory");
}

// ---------------- lengths: Lp1[b] = popcount(mask row) + 1 (CLS) -------------
__global__ __launch_bounds__(256) void k_len(const int* __restrict__ mask,
                                             int* __restrict__ lens) {
  int b = blockIdx.x, t = threadIdx.x;
  int s = 0;
  for (int j = t; j < NMASK_; j += 256) s += (mask[b * NMASK_ + j] != 0) ? 1 : 0;
  __shared__ int red[256];
  red[t] = s; __syncthreads();
  for (int st = 128; st > 0; st >>= 1) { if (t < st) red[t] += red[t + st]; __syncthreads(); }
  if (t == 0) lens[b] = red[0] + 1;
}

// ---------------- x -> bf16 ---------------------------------------------------
__global__ __launch_bounds__(256) void k_cvt_x(const float* __restrict__ x,
                                               u16* __restrict__ xb, int n4) {
  int i = blockIdx.x * 256 + threadIdx.x;
  if (i >= n4) return;
  float4 v = ((const float4*)x)[i];
  u16x4 o;
  o[0] = rne_bf16(v.x); o[1] = rne_bf16(v.y); o[2] = rne_bf16(v.z); o[3] = rne_bf16(v.w);
  *(u16x4*)&xb[i * 4] = o;
}

// ---------------- transpose+convert weights: wT[c][k] = bf16(w[k][c]) --------
__global__ __launch_bounds__(256) void k_wT(const float* __restrict__ w,
                                            u16* __restrict__ wT, int R, int C) {
  __shared__ float tile[32][33];
  int c0 = blockIdx.x * 32, r0 = blockIdx.y * 32;
  int tx = threadIdx.x & 31, ty = threadIdx.x >> 5;   // 32 x 8
  #pragma unroll
  for (int i = 0; i < 32; i += 8) tile[ty + i][tx] = w[(size_t)(r0 + ty + i) * C + c0 + tx];
  __syncthreads();
  #pragma unroll
  for (int i = 0; i < 32; i += 8)
    wT[(size_t)(c0 + ty + i) * R + r0 + tx] = rne_bf16(tile[tx][ty + i]);
}

// ---------------- zero VT pad columns (j in [SEQ, NPAD)) ---------------------
__global__ __launch_bounds__(256) void k_zpad(u16* __restrict__ VT) {
  int idx = blockIdx.x * 256 + threadIdx.x;
  const int PADW = NPAD - SEQ; // 31
  if (idx >= BHN * HD * PADW) return;
  int c = idx % PADW, rd = idx / PADW; // rd = bh*HD + d
  VT[(size_t)rd * NPAD + SEQ + c] = 0;
}

// ---------------- 128x128 MFMA mainloop (BK=32, dbuf + counted vmcnt) --------
__device__ __forceinline__ void gemm_ml128(const u16* __restrict__ A,
                                           const u16* __restrict__ Bt,
                                           int M, int m0, int n0,
                                           f4v acc[4][4], u16* smem) {
  const int t = threadIdx.x;
  const int w = t >> 6, l = t & 63, lg = l >> 4, lr = l & 15;
  const int wr = w >> 1, wc = w & 1;

  int rA0 = m0 + (t >> 2);       if (rA0 >= M) rA0 = M - 1;   // clamp M edge
  int rA1 = m0 + (t >> 2) + 64;  if (rA1 >= M) rA1 = M - 1;
  const u16* sA0 = A  + (size_t)rA0 * DIM + (t & 3) * 8;
  const u16* sA1 = A  + (size_t)rA1 * DIM + (t & 3) * 8;
  const u16* sB0 = Bt + (size_t)(n0 + (t >> 2)) * DIM + (t & 3) * 8;
  const u16* sB1 = Bt + (size_t)(n0 + (t >> 2) + 64) * DIM + (t & 3) * 8;
  const int dO0 = w * 512, dO1 = 2048 + w * 512;   // wave-uniform (u16 idx)

  #pragma unroll
  for (int fm = 0; fm < 4; fm++)
    #pragma unroll
    for (int fn = 0; fn < 4; fn++) { f4v z = {0.f, 0.f, 0.f, 0.f}; acc[fm][fn] = z; }

  // prologue: tile 0 -> buf 0 (4 loads in flight)
  gld16(sA0, &smem[dO0]);        gld16(sA1, &smem[dO1]);
  gld16(sB0, &smem[8192 + dO0]); gld16(sB1, &smem[8192 + dO1]);

  const int NT = DIM / 32;   // 24
  for (int kt = 0; kt < NT; ++kt) {
    const int p = kt & 1;
    if (kt + 1 < NT) {
      const int ka = (kt + 1) * 32;
      const int nb = (p ^ 1) * 4096;
      gld16(sA0 + ka, &smem[nb + dO0]);        gld16(sA1 + ka, &smem[nb + dO1]);
      gld16(sB0 + ka, &smem[8192 + nb + dO0]); gld16(sB1 + ka, &smem[8192 + nb + dO1]);
      asm volatile("s_waitcnt vmcnt(4)" ::: "memory");  // tile kt landed; kt+1 flies
    } else {
      asm volatile("s_waitcnt vmcnt(0)" ::: "memory");  // final drain
    }
    __builtin_amdgcn_sched_barrier(0);
    barrier_();                          // all waves' tile-kt data visible
    const u16* lA = &smem[p * 4096];
    const u16* lB = &smem[8192 + p * 4096];
    s8v a[4], bb[4];
    #pragma unroll
    for (int fm = 0; fm < 4; fm++) a[fm] = *(const s8v*)&lA[(wr * 64 + fm * 16 + lr) * 32 + lg * 8];
    #pragma unroll
    for (int fn = 0; fn < 4; fn++) bb[fn] = *(const s8v*)&lB[(wc * 64 + fn * 16 + lr) * 32 + lg * 8];
    #pragma unroll
    for (int fm = 0; fm < 4; fm++)
      #pragma unroll
      for (int fn = 0; fn < 4; fn++)
        acc[fm][fn] = __builtin_amdgcn_mfma_f32_16x16x32_bf16(a[fm], bb[fn], acc[fm][fn], 0, 0, 0);
    barrier_();                          // buf p reads closed before kt+2 writes it
  }
}

// ---------------- QKV GEMM + coalesced LDS-transposed scatter epilogue -------
// Q pre-scaled by 0.125*log2(e) so attention can use exp2 (1 VALU op).
__global__ __launch_bounds__(256) void k_gemm_qkv(const u16* __restrict__ xb,
                                                  const u16* __restrict__ wqkvT,
                                                  const float* __restrict__ bqkv,
                                                  const int* __restrict__ lens,
                                                  u16* __restrict__ Q,
                                                  u16* __restrict__ Kb,
                                                  u16* __restrict__ VT) {
  __shared__ alignas(16) u16 smem[16384];   // 32 KB: mainloop; then C-tile
  int m0 = blockIdx.x * 128, n0 = blockIdx.y * 128;
  const int which = n0 / DIM;               // 0=q 1=k 2=v (uniform per block)
  if (which < 2) {                          // Q or K tile: skip if all rows invalid
    int b0 = m0 / SEQ, off = m0 - b0 * SEQ;
    bool spans = (m0 + 127) >= (b0 + 1) * SEQ;
    if (!spans && off >= lens[b0]) return;
  }
  f4v acc[4][4];
  gemm_ml128(xb, wqkvT, MROWS, m0, n0, acc, smem);
  const int t = threadIdx.x;
  const int w = t >> 6, l = t & 63, lg = l >> 4, lr = l & 15;
  const int wr = w >> 1, wc = w & 1;
  const int hbase = (n0 - which * DIM) >> 6;
  const float qs = (which == 0) ? 0.18033688f : 1.0f;   // 0.125 * log2(e)

  __syncthreads();                          // mainloop LDS dead
  #pragma unroll
  for (int fn = 0; fn < 4; fn++) {
    int col = wc * 64 + fn * 16 + lr;
    float bias = bqkv[n0 + col];
    #pragma unroll
    for (int fm = 0; fm < 4; fm++)
      #pragma unroll
      for (int r = 0; r < 4; r++) {
        int row = wr * 64 + fm * 16 + lg * 4 + r;
        smem[row * 128 + col] = rne_bf16((acc[fm][fn][r] + bias) * qs);
      }
  }
  __syncthreads();

  if (which < 2) {
    // Q/K: [n][d] layout -> 16B chunks along d; wave covers 4 rows x 256 B
    u16* dst = (which == 0) ? Q : Kb;
    #pragma unroll
    for (int p = 0; p < 8; p++) {
      int c = p * 256 + t;                  // 2048 chunks
      int row = c >> 4, col = (c & 15) * 8;
      int gm = m0 + row;
      if (gm >= MROWS) continue;
      int b = gm / SEQ, n = gm - b * SEQ;
      int head = hbase + (col >> 6), d = col & 63;
      *(s8v*)&dst[((size_t)(b * HEADS + head) * NPAD + n) * HD + d] =
          *(const s8v*)&smem[row * 128 + col];
    }
  } else {
    // V: transposed [d][n] -> 16B chunks along n (8 rows gathered per chunk)
    #pragma unroll
    for (int p = 0; p < 8; p++) {
      int c = p * 256 + t;
      int d = c & 127, nb = c >> 7;         // 128 cols x 16 row-blocks
      int gm0 = m0 + nb * 8;
      if (gm0 >= MROWS) continue;
      int head = hbase + (d >> 6), dl = d & 63;
      int b0 = gm0 / SEQ;
      if (gm0 + 7 < MROWS && (gm0 + 7) < (b0 + 1) * SEQ) {     // run stays in batch
        s8v v;
        #pragma unroll
        for (int e = 0; e < 8; e++) v[e] = (short)smem[(nb * 8 + e) * 128 + d];
        int n = gm0 - b0 * SEQ;
        *(s8v*)&VT[((size_t)(b0 * HEADS + head) * HD + dl) * NPAD + n] = v;
      } else {                              // crosses batch boundary / M edge
        for (int e = 0; e < 8; e++) {
          int gm = gm0 + e;
          if (gm >= MROWS) break;
          int b = gm / SEQ, n = gm - b * SEQ;
          VT[((size_t)(b * HEADS + head) * HD + dl) * NPAD + n] = smem[(nb * 8 + e) * 128 + d];
        }
      }
    }
  }
}

// ---------------- per-(b,h) mean of V over all SEQ rows ----------------------
__global__ __launch_bounds__(256) void k_vmean(const u16* __restrict__ VT,
                                               float* __restrict__ vmean) {
  int bh = blockIdx.x, t = threadIdx.x;
  int d = t >> 2, part = t & 3;
  const u16* row = VT + (size_t)(bh * HD + d) * NPAD;
  float s = 0.f;
  for (int jc = part * 264; jc < part * 264 + 264; jc += 8) {
    if (jc + 8 <= SEQ) {
      s8v v = *(const s8v*)&row[jc];
      #pragma unroll
      for (int e = 0; e < 8; e++) s += bf2f((u16)v[e]);
    } else {
      for (int e = 0; e < 8; e++) if (jc + e < SEQ) s += bf2f(row[jc + e]);
    }
  }
  __shared__ float red[256];
  red[t] = s; __syncthreads();
  if (part == 0)
    vmean[bh * HD + d] = (red[t] + red[t + 1] + red[t + 2] + red[t + 3]) * (1.0f / (float)SEQ);
}

// ---------------- vproj[b*DIM+n] = vmean[b] . wprojT[n] + bproj[n] -----------
// wave-per-output GEMV: 6144 outputs, 4 waves/block, 1536 blocks.
__global__ __launch_bounds__(256) void k_vproj(const float* __restrict__ vmean,
                                               const u16* __restrict__ wprojT,
                                               const float* __restrict__ bproj,
                                               float* __restrict__ vproj) {
  int gid = blockIdx.x * 4 + (threadIdx.x >> 6);   // output index
  if (gid >= BATCH * DIM) return;
  int b = gid / DIM, n = gid - b * DIM;
  int l = threadIdx.x & 63;
  const u16* wr = wprojT + (size_t)n * DIM;
  const float* vm = vmean + b * DIM;
  float s = 0.f;
  #pragma unroll
  for (int i = 0; i < DIM / 64; ++i)               // 12 coalesced strided MACs
    s += vm[l + i * 64] * bf2f(wr[l + i * 64]);
  #pragma unroll
  for (int off = 32; off >= 1; off >>= 1) s += __shfl_xor(s, off);
  if (l == 0) vproj[gid] = s + bproj[n];
}

// ---------------- flash attention over the valid prefix ----------------------
// grid (96 bh, 17 qtile) — bh-major => all q-tiles of a bh share an XCD.
// 4 waves x 16 Q-rows (QBLK=64); KVBLK=64; T14 reg-staged issue-early.
// NO-MAX + EXP2 softmax: Q pre-scaled by 0.125*log2(e) => P=exp2(s) (single
// v_exp_f32); masked -> exp2(-1e30)=+0. Softmax scale-invariant.
__global__ __launch_bounds__(256) void k_attn(const u16* __restrict__ Q,
                                              const u16* __restrict__ Kb,
                                              const u16* __restrict__ VT,
                                              const int* __restrict__ lens,
                                              u16* __restrict__ aout) {
  int bh = blockIdx.x; int b = bh / HEADS, h = bh - b * HEADS;
  int Lp1 = lens[b];
  int q0 = blockIdx.y * 64;
  if (q0 >= Lp1) return;                      // invalid rows: vproj/bcast path
  __shared__ alignas(16) u16 Kt[64 * 64];     // [j][d], XOR-swizzled 16B granules
  __shared__ alignas(16) u16 Vt[64 * 64];     // [d][k], XOR-swizzled
  __shared__ alignas(16) u16 Pt[4][16 * 72];  // per-wave P tile, 144B stride
  const int t = threadIdx.x, w = t >> 6, l = t & 63, lg = l >> 4, lr = l & 15;
  const u16* Qbh = Q  + (size_t)bh * NPAD * HD;
  const u16* Kbh = Kb + (size_t)bh * NPAD * HD;
  const u16* Vbh = VT + (size_t)bh * HD * NPAD;

  int qi = q0 + w * 16 + lr;                  // A-frag row (l&15)
  s8v qf[2];
  qf[0] = *(const s8v*)&Qbh[(size_t)qi * HD +      lg * 8];
  qf[1] = *(const s8v*)&Qbh[(size_t)qi * HD + 32 + lg * 8];

  f4v o[4];
  #pragma unroll
  for (int fd = 0; fd < 4; fd++) { f4v z = {0.f, 0.f, 0.f, 0.f}; o[fd] = z; }
  float ssacc[4];                             // per-lane partial row sums
  #pragma unroll
  for (int r = 0; r < 4; r++) ssacc[r] = 0.f;

  // T14 staging: per-thread row js (0..63), chunk pair cs/cs+4
  const int js = t >> 2, cs = t & 3;
  const u16* kSrc = Kbh + (size_t)js * HD   + cs * 8;
  const u16* vSrc = Vbh + (size_t)js * NPAD + cs * 8;
  const int kDst0 = js * 64 + ((cs       ^ (js & 7)) * 8);
  const int kDst1 = js * 64 + (((cs + 4) ^ (js & 7)) * 8);
  s8v kr0, kr1, vr0, vr1;
  kr0 = *(const s8v*)(kSrc);        kr1 = *(const s8v*)(kSrc + 32);   // tile 0
  vr0 = *(const s8v*)(vSrc);        vr1 = *(const s8v*)(vSrc + 32);

  for (int j0 = 0; j0 < Lp1; j0 += 64) {
    __syncthreads();                          // Kt/Vt free (prev tile consumed)
    *(s8v*)&Kt[kDst0] = kr0;  *(s8v*)&Kt[kDst1] = kr1;
    *(s8v*)&Vt[kDst0] = vr0;  *(s8v*)&Vt[kDst1] = vr1;
    if (j0 + 64 < Lp1) {                      // issue next loads: fly over compute
      kr0 = *(const s8v*)(kSrc + (size_t)(j0 + 64) * HD);
      kr1 = *(const s8v*)(kSrc + (size_t)(j0 + 64) * HD + 32);
      vr0 = *(const s8v*)(vSrc + (j0 + 64));
      vr1 = *(const s8v*)(vSrc + (j0 + 64) + 32);
    }
    __syncthreads();

    // S = Q K^T  (four 16-col j-frags, k = 64 in two steps)
    f4v sf[4];
    #pragma unroll
    for (int jf = 0; jf < 4; jf++) { f4v z = {0.f,0.f,0.f,0.f}; sf[jf] = z; }
    __builtin_amdgcn_s_setprio(1);
    #pragma unroll
    for (int jf = 0; jf < 4; jf++) {
      int j = jf * 16 + lr;                    // B-frag col (l&15)
      #pragma unroll
      for (int kf = 0; kf < 2; kf++) {
        s8v kfr = *(const s8v*)&Kt[j * 64 + (((kf * 4 + lg) ^ (j & 7)) * 8)];
        sf[jf] = __builtin_amdgcn_mfma_f32_16x16x32_bf16(qf[kf], kfr, sf[jf], 0, 0, 0);
      }
    }
    __builtin_amdgcn_s_setprio(0);

    u16* P = &Pt[w][0];
    if (j0 + 64 <= Lp1) {                     // full tile: exp2 directly
      #pragma unroll
      for (int r = 0; r < 4; r++) {
        float e0 = exp2f(sf[0][r]);
        float e1 = exp2f(sf[1][r]);
        float e2 = exp2f(sf[2][r]);
        float e3 = exp2f(sf[3][r]);
        int prow = (lg * 4 + r) * 72;
        P[prow +      lr] = rne_bf16(e0);
        P[prow + 16 + lr] = rne_bf16(e1);
        P[prow + 32 + lr] = rne_bf16(e2);
        P[prow + 48 + lr] = rne_bf16(e3);
        ssacc[r] += (e0 + e1) + (e2 + e3);
      }
    } else {                                  // tail tile: mask invalid cols
      bool ok[4];
      #pragma unroll
      for (int jf = 0; jf < 4; jf++) ok[jf] = (j0 + jf * 16 + lr) < Lp1;
      #pragma unroll
      for (int r = 0; r < 4; r++) {
        float e0 = exp2f(ok[0] ? sf[0][r] : -1e30f);  // masked/NaN -> exactly 0
        float e1 = exp2f(ok[1] ? sf[1][r] : -1e30f);
        float e2 = exp2f(ok[2] ? sf[2][r] : -1e30f);
        float e3 = exp2f(ok[3] ? sf[3][r] : -1e30f);
        int prow = (lg * 4 + r) * 72;
        P[prow +      lr] = rne_bf16(e0);
        P[prow + 16 + lr] = rne_bf16(e1);
        P[prow + 32 + lr] = rne_bf16(e2);
        P[prow + 48 + lr] = rne_bf16(e3);
        ssacc[r] += (e0 + e1) + (e2 + e3);
      }
    }
    asm volatile("s_waitcnt lgkmcnt(0)" ::: "memory");   // wave-local LDS RAW
    s8v pa[2];
    pa[0] = *(const s8v*)&P[lr * 72 +      lg * 8];
    pa[1] = *(const s8v*)&P[lr * 72 + 32 + lg * 8];
    __builtin_amdgcn_s_setprio(1);
    #pragma unroll
    for (int fd = 0; fd < 4; fd++) {
      int dv = fd * 16 + lr;
      #pragma unroll
      for (int kf = 0; kf < 2; kf++) {
        s8v vb = *(const s8v*)&Vt[dv * 64 + (((kf * 4 + lg) ^ (dv & 7)) * 8)];
        o[fd] = __builtin_amdgcn_mfma_f32_16x16x32_bf16(pa[kf], vb, o[fd], 0, 0, 0);
      }
    }
    __builtin_amdgcn_s_setprio(0);
  }

  float inv[4];
  #pragma unroll
  for (int r = 0; r < 4; r++) {               // single end reduce over 16 lanes
    float rs = ssacc[r];
    rs += __shfl_xor(rs, 1); rs += __shfl_xor(rs, 2);
    rs += __shfl_xor(rs, 4); rs += __shfl_xor(rs, 8);
    inv[r] = 1.0f / rs;
  }
  #pragma unroll
  for (int fd = 0; fd < 4; fd++)
    #pragma unroll
    for (int r = 0; r < 4; r++) {
      int i = q0 + w * 16 + lg * 4 + r;
      if (i < Lp1)
        aout[(size_t)(b * SEQ + i) * DIM + h * HD + fd * 16 + lr] = rne_bf16(o[fd][r] * inv[r]);
    }
}

// ---------------- broadcast invalid rows of out: vproj row --------------------
__global__ __launch_bounds__(256) void k_bcast(const int* __restrict__ lens,
                                               const float* __restrict__ vproj,
                                               float* __restrict__ out) {
  int idx = blockIdx.x * 256 + threadIdx.x;          // float4 index
  if (idx >= MROWS * DIM / 4) return;
  int e4 = idx * 4;
  int b = e4 / (SEQ * DIM);
  int rem = e4 - b * (SEQ * DIM);
  int i = rem / DIM;
  if (i >= lens[b]) {
    int c = rem - i * DIM;
    const float* vp = &vproj[b * DIM + c];
    float4 v = { vp[0], vp[1], vp[2], vp[3] };
    ((float4*)out)[idx] = v;
  }
}

// ---------------- output projection + bias -----------------------------------
__global__ __launch_bounds__(256) void k_gemm_proj(const u16* __restrict__ aout,
                                                   const u16* __restrict__ wprojT,
                                                   const float* __restrict__ bproj,
                                                   const int* __restrict__ lens,
                                                   float* __restrict__ out) {
  __shared__ alignas(16) u16 smem[16384];
  int m0 = blockIdx.x * 128, n0 = blockIdx.y * 128;
  {                                   // skip fully-invalid row tiles (bcast path)
    int b0 = m0 / SEQ, off = m0 - b0 * SEQ;
    bool spans = (m0 + 127) >= (b0 + 1) * SEQ;
    if (!spans && off >= lens[b0]) return;
  }
  f4v acc[4][4];
  gemm_ml128(aout, wprojT, MROWS, m0, n0, acc, smem);
  const int t = threadIdx.x;
  const int w = t >> 6, l = t & 63, lg = l >> 4, lr = l & 15;
  const int wr = w >> 1, wc = w & 1;
  #pragma unroll
  for (int fn = 0; fn < 4; fn++) {
    int gc = n0 + wc * 64 + fn * 16 + lr;
    float bias = bproj[gc];
    #pragma unroll
    for (int fm = 0; fm < 4; fm++)
      #pragma unroll
      for (int r = 0; r < 4; r++) {
        int gm = m0 + wr * 64 + fm * 16 + lg * 4 + r;
        if (gm < MROWS) out[(size_t)gm * DIM + gc] = acc[fm][fn][r] + bias;
      }
  }
}

// ---------------- launch ------------------------------------------------------
extern "C" void kernel_launch(void* const* d_in, const int* in_sizes, int n_in,
                              void* d_out, int out_size, void* d_ws, size_t ws_size,
                              hipStream_t stream) {
  const float* x      = (const float*)d_in[0];
  const int*   mask   = (const int*)  d_in[1];
  const float* w_qkv  = (const float*)d_in[2];
  const float* b_qkv  = (const float*)d_in[3];
  const float* w_proj = (const float*)d_in[4];
  const float* b_proj = (const float*)d_in[5];
  float* out = (float*)d_out;

  // workspace layout (bf16 elems); aout aliases xb (xb dead after qkv GEMM)
  u16* xb     = (u16*)d_ws;                          // 8200*768
  u16* wqkvT  = xb    + (size_t)MROWS * DIM;         // 2304*768
  u16* wprojT = wqkvT + (size_t)K3 * DIM;            // 768*768
  u16* Q      = wprojT + (size_t)DIM * DIM;          // 96*1056*64
  u16* Kb     = Q     + (size_t)BHN * NPAD * HD;
  u16* VT     = Kb    + (size_t)BHN * NPAD * HD;
  float* vmean = (float*)(VT + (size_t)BHN * NPAD * HD);
  int* lens    = (int*)(vmean + BHN * HD);
  float* vproj = (float*)(lens + 256);               // 8*768 f32
  u16* aout   = xb;                                  // alias: safe, stream-ordered
  // total ~56.3 MB of d_ws

  k_len  <<<dim3(BATCH), dim3(256), 0, stream>>>(mask, lens);
  k_cvt_x<<<dim3((MROWS * DIM / 4 + 255) / 256), dim3(256), 0, stream>>>(x, xb, MROWS * DIM / 4);
  k_wT   <<<dim3(K3 / 32, DIM / 32), dim3(256), 0, stream>>>(w_qkv, wqkvT, DIM, K3);
  k_wT   <<<dim3(DIM / 32, DIM / 32), dim3(256), 0, stream>>>(w_proj, wprojT, DIM, DIM);
  k_zpad <<<dim3((BHN * HD * (NPAD - SEQ) + 255) / 256), dim3(256), 0, stream>>>(VT);
  k_gemm_qkv<<<dim3((MROWS + 127) / 128, K3 / 128), dim3(256), 0, stream>>>(xb, wqkvT, b_qkv, lens, Q, Kb, VT);
  k_vmean<<<dim3(BHN), dim3(256), 0, stream>>>(VT, vmean);
  k_vproj<<<dim3((BATCH * DIM + 3) / 4), dim3(256), 0, stream>>>(vmean, wprojT, b_proj, vproj);
  k_attn <<<dim3(BHN, (SEQ + 63) / 64), dim3(256), 0, stream>>>(Q, Kb, VT, lens, aout);
  k_gemm_proj<<<dim3((MROWS + 127) / 128, DIM / 128), dim3(256), 0, stream>>>(aout, wprojT, b_proj, lens, out);
  k_bcast<<<dim3((MROWS * DIM / 4 + 255) / 256), dim3(256), 0, stream>>>(lens, vproj, out);
}

// Round 17
// 159.945 us; speedup vs baseline: 1.0402x; 1.0303x over previous
//
#include <hip/hip_runtime.h>
#include <stdint.h>

// Problem constants
#define BATCH   8
#define NMASK_  1024
#define SEQ     1025          // NMASK + 1 (CLS prepended)
#define NPAD    1056          // SEQ padded to multiple of 32
#define DIM     768
#define HEADS   12
#define HD      64
#define BHN     (BATCH*HEADS) // 96
#define MROWS   (BATCH*SEQ)   // 8200
#define K3      (3*DIM)       // 2304

typedef unsigned short u16;
typedef __attribute__((ext_vector_type(8))) short s8v;   // 8 bf16 (A/B frag)
typedef __attribute__((ext_vector_type(4))) float f4v;   // C/D frag
typedef __attribute__((ext_vector_type(4))) unsigned short u16x4;

__device__ __forceinline__ u16 rne_bf16(float f) {
  unsigned u = __float_as_uint(f);
  u += 0x7fffu + ((u >> 16) & 1u);      // round-to-nearest-even
  return (u16)(u >> 16);
}
__device__ __forceinline__ float bf2f(u16 u) {
  return __uint_as_float(((unsigned)u) << 16);
}

// async global->LDS, 16B per lane; LDS dest = wave-uniform base + lane*16
__device__ __forceinline__ void gld16(const u16* g, u16* l) {
  __builtin_amdgcn_global_load_lds(
      (const __attribute__((address_space(1))) void*)g,
      (__attribute__((address_space(3))) void*)l, 16, 0, 0);
}

// raw barrier with compiler memory fences (no vmcnt(0) drain inserted)
__device__ __forceinline__ void barrier_() {
  asm volatile("" ::: "memory");
  __builtin_amdgcn_s_barrier();
  asm volatile("" ::: "memory");
}

// ---------------- lengths: Lp1[b] = popcount(mask row) + 1 (CLS) -------------
__global__ __launch_bounds__(256) void k_len(const int* __restrict__ mask,
                                             int* __restrict__ lens) {
  int b = blockIdx.x, t = threadIdx.x;
  int s = 0;
  for (int j = t; j < NMASK_; j += 256) s += (mask[b * NMASK_ + j] != 0) ? 1 : 0;
  __shared__ int red[256];
  red[t] = s; __syncthreads();
  for (int st = 128; st > 0; st >>= 1) { if (t < st) red[t] += red[t + st]; __syncthreads(); }
  if (t == 0) lens[b] = red[0] + 1;
}

// ---------------- x -> bf16 ---------------------------------------------------
__global__ __launch_bounds__(256) void k_cvt_x(const float* __restrict__ x,
                                               u16* __restrict__ xb, int n4) {
  int i = blockIdx.x * 256 + threadIdx.x;
  if (i >= n4) return;
  float4 v = ((const float4*)x)[i];
  u16x4 o;
  o[0] = rne_bf16(v.x); o[1] = rne_bf16(v.y); o[2] = rne_bf16(v.z); o[3] = rne_bf16(v.w);
  *(u16x4*)&xb[i * 4] = o;
}

// ---------------- transpose+convert weights: wT[c][k] = bf16(w[k][c]) --------
__global__ __launch_bounds__(256) void k_wT(const float* __restrict__ w,
                                            u16* __restrict__ wT, int R, int C) {
  __shared__ float tile[32][33];
  int c0 = blockIdx.x * 32, r0 = blockIdx.y * 32;
  int tx = threadIdx.x & 31, ty = threadIdx.x >> 5;   // 32 x 8
  #pragma unroll
  for (int i = 0; i < 32; i += 8) tile[ty + i][tx] = w[(size_t)(r0 + ty + i) * C + c0 + tx];
  __syncthreads();
  #pragma unroll
  for (int i = 0; i < 32; i += 8)
    wT[(size_t)(c0 + ty + i) * R + r0 + tx] = rne_bf16(tile[tx][ty + i]);
}

// ---------------- zero VT pad columns (j in [SEQ, NPAD)) ---------------------
__global__ __launch_bounds__(256) void k_zpad(u16* __restrict__ VT) {
  int idx = blockIdx.x * 256 + threadIdx.x;
  const int PADW = NPAD - SEQ; // 31
  if (idx >= BHN * HD * PADW) return;
  int c = idx % PADW, rd = idx / PADW; // rd = bh*HD + d
  VT[(size_t)rd * NPAD + SEQ + c] = 0;
}

// ---------------- 128x128 MFMA mainloop (BK=32, dbuf + counted vmcnt) --------
__device__ __forceinline__ void gemm_ml128(const u16* __restrict__ A,
                                           const u16* __restrict__ Bt,
                                           int M, int m0, int n0,
                                           f4v acc[4][4], u16* smem) {
  const int t = threadIdx.x;
  const int w = t >> 6, l = t & 63, lg = l >> 4, lr = l & 15;
  const int wr = w >> 1, wc = w & 1;

  int rA0 = m0 + (t >> 2);       if (rA0 >= M) rA0 = M - 1;   // clamp M edge
  int rA1 = m0 + (t >> 2) + 64;  if (rA1 >= M) rA1 = M - 1;
  const u16* sA0 = A  + (size_t)rA0 * DIM + (t & 3) * 8;
  const u16* sA1 = A  + (size_t)rA1 * DIM + (t & 3) * 8;
  const u16* sB0 = Bt + (size_t)(n0 + (t >> 2)) * DIM + (t & 3) * 8;
  const u16* sB1 = Bt + (size_t)(n0 + (t >> 2) + 64) * DIM + (t & 3) * 8;
  const int dO0 = w * 512, dO1 = 2048 + w * 512;   // wave-uniform (u16 idx)

  #pragma unroll
  for (int fm = 0; fm < 4; fm++)
    #pragma unroll
    for (int fn = 0; fn < 4; fn++) { f4v z = {0.f, 0.f, 0.f, 0.f}; acc[fm][fn] = z; }

  // prologue: tile 0 -> buf 0 (4 loads in flight)
  gld16(sA0, &smem[dO0]);        gld16(sA1, &smem[dO1]);
  gld16(sB0, &smem[8192 + dO0]); gld16(sB1, &smem[8192 + dO1]);

  const int NT = DIM / 32;   // 24
  for (int kt = 0; kt < NT; ++kt) {
    const int p = kt & 1;
    if (kt + 1 < NT) {
      const int ka = (kt + 1) * 32;
      const int nb = (p ^ 1) * 4096;
      gld16(sA0 + ka, &smem[nb + dO0]);        gld16(sA1 + ka, &smem[nb + dO1]);
      gld16(sB0 + ka, &smem[8192 + nb + dO0]); gld16(sB1 + ka, &smem[8192 + nb + dO1]);
      asm volatile("s_waitcnt vmcnt(4)" ::: "memory");  // tile kt landed; kt+1 flies
    } else {
      asm volatile("s_waitcnt vmcnt(0)" ::: "memory");  // final drain
    }
    __builtin_amdgcn_sched_barrier(0);
    barrier_();                          // all waves' tile-kt data visible
    const u16* lA = &smem[p * 4096];
    const u16* lB = &smem[8192 + p * 4096];
    s8v a[4], bb[4];
    #pragma unroll
    for (int fm = 0; fm < 4; fm++) a[fm] = *(const s8v*)&lA[(wr * 64 + fm * 16 + lr) * 32 + lg * 8];
    #pragma unroll
    for (int fn = 0; fn < 4; fn++) bb[fn] = *(const s8v*)&lB[(wc * 64 + fn * 16 + lr) * 32 + lg * 8];
    #pragma unroll
    for (int fm = 0; fm < 4; fm++)
      #pragma unroll
      for (int fn = 0; fn < 4; fn++)
        acc[fm][fn] = __builtin_amdgcn_mfma_f32_16x16x32_bf16(a[fm], bb[fn], acc[fm][fn], 0, 0, 0);
    barrier_();                          // buf p reads closed before kt+2 writes it
  }
}

// ---------------- QKV GEMM + coalesced LDS-transposed scatter epilogue -------
__global__ __launch_bounds__(256) void k_gemm_qkv(const u16* __restrict__ xb,
                                                  const u16* __restrict__ wqkvT,
                                                  const float* __restrict__ bqkv,
                                                  const int* __restrict__ lens,
                                                  u16* __restrict__ Q,
                                                  u16* __restrict__ Kb,
                                                  u16* __restrict__ VT) {
  __shared__ alignas(16) u16 smem[16384];   // 32 KB: mainloop; then C-tile
  int m0 = blockIdx.x * 128, n0 = blockIdx.y * 128;
  const int which = n0 / DIM;               // 0=q 1=k 2=v (uniform per block)
  if (which < 2) {                          // Q or K tile: skip if all rows invalid
    int b0 = m0 / SEQ, off = m0 - b0 * SEQ;
    bool spans = (m0 + 127) >= (b0 + 1) * SEQ;
    if (!spans && off >= lens[b0]) return;
  }
  f4v acc[4][4];
  gemm_ml128(xb, wqkvT, MROWS, m0, n0, acc, smem);
  const int t = threadIdx.x;
  const int w = t >> 6, l = t & 63, lg = l >> 4, lr = l & 15;
  const int wr = w >> 1, wc = w & 1;
  const int hbase = (n0 - which * DIM) >> 6;
  const float qs = (which == 0) ? 0.125f : 1.0f;

  __syncthreads();                          // mainloop LDS dead
  #pragma unroll
  for (int fn = 0; fn < 4; fn++) {
    int col = wc * 64 + fn * 16 + lr;
    float bias = bqkv[n0 + col];
    #pragma unroll
    for (int fm = 0; fm < 4; fm++)
      #pragma unroll
      for (int r = 0; r < 4; r++) {
        int row = wr * 64 + fm * 16 + lg * 4 + r;
        smem[row * 128 + col] = rne_bf16((acc[fm][fn][r] + bias) * qs);
      }
  }
  __syncthreads();

  if (which < 2) {
    // Q/K: [n][d] layout -> 16B chunks along d; wave covers 4 rows x 256 B
    u16* dst = (which == 0) ? Q : Kb;
    #pragma unroll
    for (int p = 0; p < 8; p++) {
      int c = p * 256 + t;                  // 2048 chunks
      int row = c >> 4, col = (c & 15) * 8;
      int gm = m0 + row;
      if (gm >= MROWS) continue;
      int b = gm / SEQ, n = gm - b * SEQ;
      int head = hbase + (col >> 6), d = col & 63;
      *(s8v*)&dst[((size_t)(b * HEADS + head) * NPAD + n) * HD + d] =
          *(const s8v*)&smem[row * 128 + col];
    }
  } else {
    // V: transposed [d][n] -> 16B chunks along n (8 rows gathered per chunk)
    #pragma unroll
    for (int p = 0; p < 8; p++) {
      int c = p * 256 + t;
      int d = c & 127, nb = c >> 7;         // 128 cols x 16 row-blocks
      int gm0 = m0 + nb * 8;
      if (gm0 >= MROWS) continue;
      int head = hbase + (d >> 6), dl = d & 63;
      int b0 = gm0 / SEQ;
      if (gm0 + 7 < MROWS && (gm0 + 7) < (b0 + 1) * SEQ) {     // run stays in batch
        s8v v;
        #pragma unroll
        for (int e = 0; e < 8; e++) v[e] = (short)smem[(nb * 8 + e) * 128 + d];
        int n = gm0 - b0 * SEQ;
        *(s8v*)&VT[((size_t)(b0 * HEADS + head) * HD + dl) * NPAD + n] = v;
      } else {                              // crosses batch boundary / M edge
        for (int e = 0; e < 8; e++) {
          int gm = gm0 + e;
          if (gm >= MROWS) break;
          int b = gm / SEQ, n = gm - b * SEQ;
          VT[((size_t)(b * HEADS + head) * HD + dl) * NPAD + n] = smem[(nb * 8 + e) * 128 + d];
        }
      }
    }
  }
}

// ---------------- per-(b,h) mean of V over all SEQ rows ----------------------
__global__ __launch_bounds__(256) void k_vmean(const u16* __restrict__ VT,
                                               float* __restrict__ vmean) {
  int bh = blockIdx.x, t = threadIdx.x;
  int d = t >> 2, part = t & 3;
  const u16* row = VT + (size_t)(bh * HD + d) * NPAD;
  float s = 0.f;
  for (int jc = part * 264; jc < part * 264 + 264; jc += 8) {
    if (jc + 8 <= SEQ) {
      s8v v = *(const s8v*)&row[jc];
      #pragma unroll
      for (int e = 0; e < 8; e++) s += bf2f((u16)v[e]);
    } else {
      for (int e = 0; e < 8; e++) if (jc + e < SEQ) s += bf2f(row[jc + e]);
    }
  }
  __shared__ float red[256];
  red[t] = s; __syncthreads();
  if (part == 0)
    vmean[bh * HD + d] = (red[t] + red[t + 1] + red[t + 2] + red[t + 3]) * (1.0f / (float)SEQ);
}

// ---------------- vproj[b*DIM+n] = vmean[b] . wprojT[n] + bproj[n] -----------
// wave-per-output GEMV: 6144 outputs, 4 waves/block, 1536 blocks.
__global__ __launch_bounds__(256) void k_vproj(const float* __restrict__ vmean,
                                               const u16* __restrict__ wprojT,
                                               const float* __restrict__ bproj,
                                               float* __restrict__ vproj) {
  int gid = blockIdx.x * 4 + (threadIdx.x >> 6);   // output index
  if (gid >= BATCH * DIM) return;
  int b = gid / DIM, n = gid - b * DIM;
  int l = threadIdx.x & 63;
  const u16* wr = wprojT + (size_t)n * DIM;
  const float* vm = vmean + b * DIM;
  float s = 0.f;
  #pragma unroll
  for (int i = 0; i < DIM / 64; ++i)               // 12 coalesced strided MACs
    s += vm[l + i * 64] * bf2f(wr[l + i * 64]);
  #pragma unroll
  for (int off = 32; off >= 1; off >>= 1) s += __shfl_xor(s, off);
  if (l == 0) vproj[gid] = s + bproj[n];
}

// ---------------- flash attention over the valid prefix ----------------------
// grid (96 bh, 17 qtile) — bh-major => all q-tiles of a bh share an XCD.
// 4 waves x 16 Q-rows (QBLK=64); KVBLK=64; T14 reg-staged issue-early.
// NO-MAX softmax: P=exp(s) directly (|s| << 88); masked -> exp(-1e30)=+0.
__global__ __launch_bounds__(256) void k_attn(const u16* __restrict__ Q,
                                              const u16* __restrict__ Kb,
                                              const u16* __restrict__ VT,
                                              const int* __restrict__ lens,
                                              u16* __restrict__ aout) {
  int bh = blockIdx.x; int b = bh / HEADS, h = bh - b * HEADS;
  int Lp1 = lens[b];
  int q0 = blockIdx.y * 64;
  if (q0 >= Lp1) return;                      // invalid rows: vproj/bcast path
  __shared__ alignas(16) u16 Kt[64 * 64];     // [j][d], XOR-swizzled 16B granules
  __shared__ alignas(16) u16 Vt[64 * 64];     // [d][k], XOR-swizzled
  __shared__ alignas(16) u16 Pt[4][16 * 72];  // per-wave P tile, 144B stride
  const int t = threadIdx.x, w = t >> 6, l = t & 63, lg = l >> 4, lr = l & 15;
  const u16* Qbh = Q  + (size_t)bh * NPAD * HD;
  const u16* Kbh = Kb + (size_t)bh * NPAD * HD;
  const u16* Vbh = VT + (size_t)bh * HD * NPAD;

  int qi = q0 + w * 16 + lr;                  // A-frag row (l&15)
  s8v qf[2];
  qf[0] = *(const s8v*)&Qbh[(size_t)qi * HD +      lg * 8];
  qf[1] = *(const s8v*)&Qbh[(size_t)qi * HD + 32 + lg * 8];

  f4v o[4];
  #pragma unroll
  for (int fd = 0; fd < 4; fd++) { f4v z = {0.f, 0.f, 0.f, 0.f}; o[fd] = z; }
  float ssacc[4];                             // per-lane partial row sums
  #pragma unroll
  for (int r = 0; r < 4; r++) ssacc[r] = 0.f;

  // T14 staging: per-thread row js (0..63), chunk pair cs/cs+4
  const int js = t >> 2, cs = t & 3;
  const u16* kSrc = Kbh + (size_t)js * HD   + cs * 8;
  const u16* vSrc = Vbh + (size_t)js * NPAD + cs * 8;
  const int kDst0 = js * 64 + ((cs       ^ (js & 7)) * 8);
  const int kDst1 = js * 64 + (((cs + 4) ^ (js & 7)) * 8);
  s8v kr0, kr1, vr0, vr1;
  kr0 = *(const s8v*)(kSrc);        kr1 = *(const s8v*)(kSrc + 32);   // tile 0
  vr0 = *(const s8v*)(vSrc);        vr1 = *(const s8v*)(vSrc + 32);

  for (int j0 = 0; j0 < Lp1; j0 += 64) {
    __syncthreads();                          // Kt/Vt free (prev tile consumed)
    *(s8v*)&Kt[kDst0] = kr0;  *(s8v*)&Kt[kDst1] = kr1;
    *(s8v*)&Vt[kDst0] = vr0;  *(s8v*)&Vt[kDst1] = vr1;
    if (j0 + 64 < Lp1) {                      // issue next loads: fly over compute
      kr0 = *(const s8v*)(kSrc + (size_t)(j0 + 64) * HD);
      kr1 = *(const s8v*)(kSrc + (size_t)(j0 + 64) * HD + 32);
      vr0 = *(const s8v*)(vSrc + (j0 + 64));
      vr1 = *(const s8v*)(vSrc + (j0 + 64) + 32);
    }
    __syncthreads();

    // S = Q K^T  (four 16-col j-frags, k = 64 in two steps)
    f4v sf[4];
    #pragma unroll
    for (int jf = 0; jf < 4; jf++) { f4v z = {0.f,0.f,0.f,0.f}; sf[jf] = z; }
    __builtin_amdgcn_s_setprio(1);
    #pragma unroll
    for (int jf = 0; jf < 4; jf++) {
      int j = jf * 16 + lr;                    // B-frag col (l&15)
      #pragma unroll
      for (int kf = 0; kf < 2; kf++) {
        s8v kfr = *(const s8v*)&Kt[j * 64 + (((kf * 4 + lg) ^ (j & 7)) * 8)];
        sf[jf] = __builtin_amdgcn_mfma_f32_16x16x32_bf16(qf[kf], kfr, sf[jf], 0, 0, 0);
      }
    }
    __builtin_amdgcn_s_setprio(0);

    u16* P = &Pt[w][0];
    if (j0 + 64 <= Lp1) {                     // full tile: exp directly
      #pragma unroll
      for (int r = 0; r < 4; r++) {
        float e0 = __expf(sf[0][r]);
        float e1 = __expf(sf[1][r]);
        float e2 = __expf(sf[2][r]);
        float e3 = __expf(sf[3][r]);
        int prow = (lg * 4 + r) * 72;
        P[prow +      lr] = rne_bf16(e0);
        P[prow + 16 + lr] = rne_bf16(e1);
        P[prow + 32 + lr] = rne_bf16(e2);
        P[prow + 48 + lr] = rne_bf16(e3);
        ssacc[r] += (e0 + e1) + (e2 + e3);
      }
    } else {                                  // tail tile: mask invalid cols
      bool ok[4];
      #pragma unroll
      for (int jf = 0; jf < 4; jf++) ok[jf] = (j0 + jf * 16 + lr) < Lp1;
      #pragma unroll
      for (int r = 0; r < 4; r++) {
        float e0 = __expf(ok[0] ? sf[0][r] : -1e30f);  // masked/NaN -> exactly 0
        float e1 = __expf(ok[1] ? sf[1][r] : -1e30f);
        float e2 = __expf(ok[2] ? sf[2][r] : -1e30f);
        float e3 = __expf(ok[3] ? sf[3][r] : -1e30f);
        int prow = (lg * 4 + r) * 72;
        P[prow +      lr] = rne_bf16(e0);
        P[prow + 16 + lr] = rne_bf16(e1);
        P[prow + 32 + lr] = rne_bf16(e2);
        P[prow + 48 + lr] = rne_bf16(e3);
        ssacc[r] += (e0 + e1) + (e2 + e3);
      }
    }
    asm volatile("s_waitcnt lgkmcnt(0)" ::: "memory");   // wave-local LDS RAW
    s8v pa[2];
    pa[0] = *(const s8v*)&P[lr * 72 +      lg * 8];
    pa[1] = *(const s8v*)&P[lr * 72 + 32 + lg * 8];
    __builtin_amdgcn_s_setprio(1);
    #pragma unroll
    for (int fd = 0; fd < 4; fd++) {
      int dv = fd * 16 + lr;
      #pragma unroll
      for (int kf = 0; kf < 2; kf++) {
        s8v vb = *(const s8v*)&Vt[dv * 64 + (((kf * 4 + lg) ^ (dv & 7)) * 8)];
        o[fd] = __builtin_amdgcn_mfma_f32_16x16x32_bf16(pa[kf], vb, o[fd], 0, 0, 0);
      }
    }
    __builtin_amdgcn_s_setprio(0);
  }

  float inv[4];
  #pragma unroll
  for (int r = 0; r < 4; r++) {               // single end reduce over 16 lanes
    float rs = ssacc[r];
    rs += __shfl_xor(rs, 1); rs += __shfl_xor(rs, 2);
    rs += __shfl_xor(rs, 4); rs += __shfl_xor(rs, 8);
    inv[r] = 1.0f / rs;
  }
  #pragma unroll
  for (int fd = 0; fd < 4; fd++)
    #pragma unroll
    for (int r = 0; r < 4; r++) {
      int i = q0 + w * 16 + lg * 4 + r;
      if (i < Lp1)
        aout[(size_t)(b * SEQ + i) * DIM + h * HD + fd * 16 + lr] = rne_bf16(o[fd][r] * inv[r]);
    }
}

// ---------------- broadcast invalid rows of out: vproj row --------------------
__global__ __launch_bounds__(256) void k_bcast(const int* __restrict__ lens,
                                               const float* __restrict__ vproj,
                                               float* __restrict__ out) {
  int idx = blockIdx.x * 256 + threadIdx.x;          // float4 index
  if (idx >= MROWS * DIM / 4) return;
  int e4 = idx * 4;
  int b = e4 / (SEQ * DIM);
  int rem = e4 - b * (SEQ * DIM);
  int i = rem / DIM;
  if (i >= lens[b]) {
    int c = rem - i * DIM;
    const float* vp = &vproj[b * DIM + c];
    float4 v = { vp[0], vp[1], vp[2], vp[3] };
    ((float4*)out)[idx] = v;
  }
}

// ---------------- output projection + bias -----------------------------------
__global__ __launch_bounds__(256) void k_gemm_proj(const u16* __restrict__ aout,
                                                   const u16* __restrict__ wprojT,
                                                   const float* __restrict__ bproj,
                                                   const int* __restrict__ lens,
                                                   float* __restrict__ out) {
  __shared__ alignas(16) u16 smem[16384];
  int m0 = blockIdx.x * 128, n0 = blockIdx.y * 128;
  {                                   // skip fully-invalid row tiles (bcast path)
    int b0 = m0 / SEQ, off = m0 - b0 * SEQ;
    bool spans = (m0 + 127) >= (b0 + 1) * SEQ;
    if (!spans && off >= lens[b0]) return;
  }
  f4v acc[4][4];
  gemm_ml128(aout, wprojT, MROWS, m0, n0, acc, smem);
  const int t = threadIdx.x;
  const int w = t >> 6, l = t & 63, lg = l >> 4, lr = l & 15;
  const int wr = w >> 1, wc = w & 1;
  #pragma unroll
  for (int fn = 0; fn < 4; fn++) {
    int gc = n0 + wc * 64 + fn * 16 + lr;
    float bias = bproj[gc];
    #pragma unroll
    for (int fm = 0; fm < 4; fm++)
      #pragma unroll
      for (int r = 0; r < 4; r++) {
        int gm = m0 + wr * 64 + fm * 16 + lg * 4 + r;
        if (gm < MROWS) out[(size_t)gm * DIM + gc] = acc[fm][fn][r] + bias;
      }
  }
}

// ---------------- launch ------------------------------------------------------
extern "C" void kernel_launch(void* const* d_in, const int* in_sizes, int n_in,
                              void* d_out, int out_size, void* d_ws, size_t ws_size,
                              hipStream_t stream) {
  const float* x      = (const float*)d_in[0];
  const int*   mask   = (const int*)  d_in[1];
  const float* w_qkv  = (const float*)d_in[2];
  const float* b_qkv  = (const float*)d_in[3];
  const float* w_proj = (const float*)d_in[4];
  const float* b_proj = (const float*)d_in[5];
  float* out = (float*)d_out;

  // workspace layout (bf16 elems); aout aliases xb (xb dead after qkv GEMM)
  u16* xb     = (u16*)d_ws;                          // 8200*768
  u16* wqkvT  = xb    + (size_t)MROWS * DIM;         // 2304*768
  u16* wprojT = wqkvT + (size_t)K3 * DIM;            // 768*768
  u16* Q      = wprojT + (size_t)DIM * DIM;          // 96*1056*64
  u16* Kb     = Q     + (size_t)BHN * NPAD * HD;
  u16* VT     = Kb    + (size_t)BHN * NPAD * HD;
  float* vmean = (float*)(VT + (size_t)BHN * NPAD * HD);
  int* lens    = (int*)(vmean + BHN * HD);
  float* vproj = (float*)(lens + 256);               // 8*768 f32
  u16* aout   = xb;                                  // alias: safe, stream-ordered
  // total ~56.3 MB of d_ws

  k_len  <<<dim3(BATCH), dim3(256), 0, stream>>>(mask, lens);
  k_cvt_x<<<dim3((MROWS * DIM / 4 + 255) / 256), dim3(256), 0, stream>>>(x, xb, MROWS * DIM / 4);
  k_wT   <<<dim3(K3 / 32, DIM / 32), dim3(256), 0, stream>>>(w_qkv, wqkvT, DIM, K3);
  k_wT   <<<dim3(DIM / 32, DIM / 32), dim3(256), 0, stream>>>(w_proj, wprojT, DIM, DIM);
  k_zpad <<<dim3((BHN * HD * (NPAD - SEQ) + 255) / 256), dim3(256), 0, stream>>>(VT);
  k_gemm_qkv<<<dim3((MROWS + 127) / 128, K3 / 128), dim3(256), 0, stream>>>(xb, wqkvT, b_qkv, lens, Q, Kb, VT);
  k_vmean<<<dim3(BHN), dim3(256), 0, stream>>>(VT, vmean);
  k_vproj<<<dim3((BATCH * DIM + 3) / 4), dim3(256), 0, stream>>>(vmean, wprojT, b_proj, vproj);
  k_attn <<<dim3(BHN, (SEQ + 63) / 64), dim3(256), 0, stream>>>(Q, Kb, VT, lens, aout);
  k_gemm_proj<<<dim3((MROWS + 127) / 128, DIM / 128), dim3(256), 0, stream>>>(aout, wprojT, b_proj, lens, out);
  k_bcast<<<dim3((MROWS * DIM / 4 + 255) / 256), dim3(256), 0, stream>>>(lens, vproj, out);
}

// Round 18
// 158.801 us; speedup vs baseline: 1.0477x; 1.0072x over previous
//
#include <hip/hip_runtime.h>
#include <stdint.h>

// Problem constants
#define BATCH   8
#define NMASK_  1024
#define SEQ     1025          // NMASK + 1 (CLS prepended)
#define NPAD    1056          // SEQ padded to multiple of 32
#define DIM     768
#define HEADS   12
#define HD      64
#define BHN     (BATCH*HEADS) // 96
#define MROWS   (BATCH*SEQ)   // 8200
#define K3      (3*DIM)       // 2304
#define MT      65            // m-tiles (ceil(8200/128))

typedef unsigned short u16;
typedef __attribute__((ext_vector_type(8))) short s8v;   // 8 bf16 (A/B frag)
typedef __attribute__((ext_vector_type(4))) float f4v;   // C/D frag
typedef __attribute__((ext_vector_type(4))) unsigned short u16x4;

__device__ __forceinline__ u16 rne_bf16(float f) {
  unsigned u = __float_as_uint(f);
  u += 0x7fffu + ((u >> 16) & 1u);      // round-to-nearest-even
  return (u16)(u >> 16);
}
__device__ __forceinline__ float bf2f(u16 u) {
  return __uint_as_float(((unsigned)u) << 16);
}

// async global->LDS, 16B per lane; LDS dest = wave-uniform base + lane*16
__device__ __forceinline__ void gld16(const u16* g, u16* l) {
  __builtin_amdgcn_global_load_lds(
      (const __attribute__((address_space(1))) void*)g,
      (__attribute__((address_space(3))) void*)l, 16, 0, 0);
}

// raw barrier with compiler memory fences (no vmcnt(0) drain inserted)
__device__ __forceinline__ void barrier_() {
  asm volatile("" ::: "memory");
  __builtin_amdgcn_s_barrier();
  asm volatile("" ::: "memory");
}

// ---------------- lengths: Lp1[b] = popcount(mask row) + 1 (CLS) -------------
__global__ __launch_bounds__(256) void k_len(const int* __restrict__ mask,
                                             int* __restrict__ lens) {
  int b = blockIdx.x, t = threadIdx.x;
  int s = 0;
  for (int j = t; j < NMASK_; j += 256) s += (mask[b * NMASK_ + j] != 0) ? 1 : 0;
  __shared__ int red[256];
  red[t] = s; __syncthreads();
  for (int st = 128; st > 0; st >>= 1) { if (t < st) red[t] += red[t + st]; __syncthreads(); }
  if (t == 0) lens[b] = red[0] + 1;
}

// ---------------- x -> bf16 ---------------------------------------------------
__global__ __launch_bounds__(256) void k_cvt_x(const float* __restrict__ x,
                                               u16* __restrict__ xb, int n4) {
  int i = blockIdx.x * 256 + threadIdx.x;
  if (i >= n4) return;
  float4 v = ((const float4*)x)[i];
  u16x4 o;
  o[0] = rne_bf16(v.x); o[1] = rne_bf16(v.y); o[2] = rne_bf16(v.z); o[3] = rne_bf16(v.w);
  *(u16x4*)&xb[i * 4] = o;
}

// ---------------- transpose+convert weights: wT[c][k] = bf16(w[k][c]) --------
__global__ __launch_bounds__(256) void k_wT(const float* __restrict__ w,
                                            u16* __restrict__ wT, int R, int C) {
  __shared__ float tile[32][33];
  int c0 = blockIdx.x * 32, r0 = blockIdx.y * 32;
  int tx = threadIdx.x & 31, ty = threadIdx.x >> 5;   // 32 x 8
  #pragma unroll
  for (int i = 0; i < 32; i += 8) tile[ty + i][tx] = w[(size_t)(r0 + ty + i) * C + c0 + tx];
  __syncthreads();
  #pragma unroll
  for (int i = 0; i < 32; i += 8)
    wT[(size_t)(c0 + ty + i) * R + r0 + tx] = rne_bf16(tile[tx][ty + i]);
}

// ---------------- zero VT pad columns (j in [SEQ, NPAD)) ---------------------
__global__ __launch_bounds__(256) void k_zpad(u16* __restrict__ VT) {
  int idx = blockIdx.x * 256 + threadIdx.x;
  const int PADW = NPAD - SEQ; // 31
  if (idx >= BHN * HD * PADW) return;
  int c = idx % PADW, rd = idx / PADW; // rd = bh*HD + d
  VT[(size_t)rd * NPAD + SEQ + c] = 0;
}

// ---------------- 128x128 MFMA mainloop (BK=32, dbuf + counted vmcnt) --------
__device__ __forceinline__ void gemm_ml128(const u16* __restrict__ A,
                                           const u16* __restrict__ Bt,
                                           int M, int m0, int n0,
                                           f4v acc[4][4], u16* smem) {
  const int t = threadIdx.x;
  const int w = t >> 6, l = t & 63, lg = l >> 4, lr = l & 15;
  const int wr = w >> 1, wc = w & 1;

  int rA0 = m0 + (t >> 2);       if (rA0 >= M) rA0 = M - 1;   // clamp M edge
  int rA1 = m0 + (t >> 2) + 64;  if (rA1 >= M) rA1 = M - 1;
  const u16* sA0 = A  + (size_t)rA0 * DIM + (t & 3) * 8;
  const u16* sA1 = A  + (size_t)rA1 * DIM + (t & 3) * 8;
  const u16* sB0 = Bt + (size_t)(n0 + (t >> 2)) * DIM + (t & 3) * 8;
  const u16* sB1 = Bt + (size_t)(n0 + (t >> 2) + 64) * DIM + (t & 3) * 8;
  const int dO0 = w * 512, dO1 = 2048 + w * 512;   // wave-uniform (u16 idx)

  #pragma unroll
  for (int fm = 0; fm < 4; fm++)
    #pragma unroll
    for (int fn = 0; fn < 4; fn++) { f4v z = {0.f, 0.f, 0.f, 0.f}; acc[fm][fn] = z; }

  // prologue: tile 0 -> buf 0 (4 loads in flight)
  gld16(sA0, &smem[dO0]);        gld16(sA1, &smem[dO1]);
  gld16(sB0, &smem[8192 + dO0]); gld16(sB1, &smem[8192 + dO1]);

  const int NT = DIM / 32;   // 24
  for (int kt = 0; kt < NT; ++kt) {
    const int p = kt & 1;
    if (kt + 1 < NT) {
      const int ka = (kt + 1) * 32;
      const int nb = (p ^ 1) * 4096;
      gld16(sA0 + ka, &smem[nb + dO0]);        gld16(sA1 + ka, &smem[nb + dO1]);
      gld16(sB0 + ka, &smem[8192 + nb + dO0]); gld16(sB1 + ka, &smem[8192 + nb + dO1]);
      asm volatile("s_waitcnt vmcnt(4)" ::: "memory");  // tile kt landed; kt+1 flies
    } else {
      asm volatile("s_waitcnt vmcnt(0)" ::: "memory");  // final drain
    }
    __builtin_amdgcn_sched_barrier(0);
    barrier_();                          // all waves' tile-kt data visible
    const u16* lA = &smem[p * 4096];
    const u16* lB = &smem[8192 + p * 4096];
    s8v a[4], bb[4];
    #pragma unroll
    for (int fm = 0; fm < 4; fm++) a[fm] = *(const s8v*)&lA[(wr * 64 + fm * 16 + lr) * 32 + lg * 8];
    #pragma unroll
    for (int fn = 0; fn < 4; fn++) bb[fn] = *(const s8v*)&lB[(wc * 64 + fn * 16 + lr) * 32 + lg * 8];
    #pragma unroll
    for (int fm = 0; fm < 4; fm++)
      #pragma unroll
      for (int fn = 0; fn < 4; fn++)
        acc[fm][fn] = __builtin_amdgcn_mfma_f32_16x16x32_bf16(a[fm], bb[fn], acc[fm][fn], 0, 0, 0);
    barrier_();                          // buf p reads closed before kt+2 writes it
  }
}

// ---------------- QKV GEMM + coalesced LDS-transposed scatter epilogue -------
// Grid (8, 162): XCD-affine mapping — A-tile x = bx + 8*(j/18) so all blocks
// sharing an A-panel have linear id == bx (mod 8) -> same XCD L2 (per-XCD
// A-footprint 1.7 MB fits 4 MB L2; was 12.6 MB x 8 XCDs = 93 MB refetch).
__global__ __launch_bounds__(256) void k_gemm_qkv(const u16* __restrict__ xb,
                                                  const u16* __restrict__ wqkvT,
                                                  const float* __restrict__ bqkv,
                                                  const int* __restrict__ lens,
                                                  u16* __restrict__ Q,
                                                  u16* __restrict__ Kb,
                                                  u16* __restrict__ VT) {
  __shared__ alignas(16) u16 smem[16384];   // 32 KB: mainloop; then C-tile
  const int jj = blockIdx.y;
  const int x = (int)blockIdx.x + 8 * (jj / 18);
  if (x >= MT) return;                      // dummy pad block
  int m0 = x * 128, n0 = (jj % 18) * 128;
  const int which = n0 / DIM;               // 0=q 1=k 2=v (uniform per block)
  if (which < 2) {                          // Q or K tile: skip if all rows invalid
    int b0 = m0 / SEQ, off = m0 - b0 * SEQ;
    bool spans = (m0 + 127) >= (b0 + 1) * SEQ;
    if (!spans && off >= lens[b0]) return;
  }
  f4v acc[4][4];
  gemm_ml128(xb, wqkvT, MROWS, m0, n0, acc, smem);
  const int t = threadIdx.x;
  const int w = t >> 6, l = t & 63, lg = l >> 4, lr = l & 15;
  const int wr = w >> 1, wc = w & 1;
  const int hbase = (n0 - which * DIM) >> 6;
  const float qs = (which == 0) ? 0.125f : 1.0f;

  __syncthreads();                          // mainloop LDS dead
  #pragma unroll
  for (int fn = 0; fn < 4; fn++) {
    int col = wc * 64 + fn * 16 + lr;
    float bias = bqkv[n0 + col];
    #pragma unroll
    for (int fm = 0; fm < 4; fm++)
      #pragma unroll
      for (int r = 0; r < 4; r++) {
        int row = wr * 64 + fm * 16 + lg * 4 + r;
        smem[row * 128 + col] = rne_bf16((acc[fm][fn][r] + bias) * qs);
      }
  }
  __syncthreads();

  if (which < 2) {
    // Q/K: [n][d] layout -> 16B chunks along d; wave covers 4 rows x 256 B
    u16* dst = (which == 0) ? Q : Kb;
    #pragma unroll
    for (int p = 0; p < 8; p++) {
      int c = p * 256 + t;                  // 2048 chunks
      int row = c >> 4, col = (c & 15) * 8;
      int gm = m0 + row;
      if (gm >= MROWS) continue;
      int b = gm / SEQ, n = gm - b * SEQ;
      int head = hbase + (col >> 6), d = col & 63;
      *(s8v*)&dst[((size_t)(b * HEADS + head) * NPAD + n) * HD + d] =
          *(const s8v*)&smem[row * 128 + col];
    }
  } else {
    // V: transposed [d][n] -> 16B chunks along n (8 rows gathered per chunk)
    #pragma unroll
    for (int p = 0; p < 8; p++) {
      int c = p * 256 + t;
      int d = c & 127, nb = c >> 7;         // 128 cols x 16 row-blocks
      int gm0 = m0 + nb * 8;
      if (gm0 >= MROWS) continue;
      int head = hbase + (d >> 6), dl = d & 63;
      int b0 = gm0 / SEQ;
      if (gm0 + 7 < MROWS && (gm0 + 7) < (b0 + 1) * SEQ) {     // run stays in batch
        s8v v;
        #pragma unroll
        for (int e = 0; e < 8; e++) v[e] = (short)smem[(nb * 8 + e) * 128 + d];
        int n = gm0 - b0 * SEQ;
        *(s8v*)&VT[((size_t)(b0 * HEADS + head) * HD + dl) * NPAD + n] = v;
      } else {                              // crosses batch boundary / M edge
        for (int e = 0; e < 8; e++) {
          int gm = gm0 + e;
          if (gm >= MROWS) break;
          int b = gm / SEQ, n = gm - b * SEQ;
          VT[((size_t)(b * HEADS + head) * HD + dl) * NPAD + n] = smem[(nb * 8 + e) * 128 + d];
        }
      }
    }
  }
}

// ---------------- per-(b,h) mean of V over all SEQ rows ----------------------
__global__ __launch_bounds__(256) void k_vmean(const u16* __restrict__ VT,
                                               float* __restrict__ vmean) {
  int bh = blockIdx.x, t = threadIdx.x;
  int d = t >> 2, part = t & 3;
  const u16* row = VT + (size_t)(bh * HD + d) * NPAD;
  float s = 0.f;
  for (int jc = part * 264; jc < part * 264 + 264; jc += 8) {
    if (jc + 8 <= SEQ) {
      s8v v = *(const s8v*)&row[jc];
      #pragma unroll
      for (int e = 0; e < 8; e++) s += bf2f((u16)v[e]);
    } else {
      for (int e = 0; e < 8; e++) if (jc + e < SEQ) s += bf2f(row[jc + e]);
    }
  }
  __shared__ float red[256];
  red[t] = s; __syncthreads();
  if (part == 0)
    vmean[bh * HD + d] = (red[t] + red[t + 1] + red[t + 2] + red[t + 3]) * (1.0f / (float)SEQ);
}

// ---------------- vproj[b*DIM+n] = vmean[b] . wprojT[n] + bproj[n] -----------
// wave-per-output GEMV: 6144 outputs, 4 waves/block, 1536 blocks.
__global__ __launch_bounds__(256) void k_vproj(const float* __restrict__ vmean,
                                               const u16* __restrict__ wprojT,
                                               const float* __restrict__ bproj,
                                               float* __restrict__ vproj) {
  int gid = blockIdx.x * 4 + (threadIdx.x >> 6);   // output index
  if (gid >= BATCH * DIM) return;
  int b = gid / DIM, n = gid - b * DIM;
  int l = threadIdx.x & 63;
  const u16* wr = wprojT + (size_t)n * DIM;
  const float* vm = vmean + b * DIM;
  float s = 0.f;
  #pragma unroll
  for (int i = 0; i < DIM / 64; ++i)               // 12 coalesced strided MACs
    s += vm[l + i * 64] * bf2f(wr[l + i * 64]);
  #pragma unroll
  for (int off = 32; off >= 1; off >>= 1) s += __shfl_xor(s, off);
  if (l == 0) vproj[gid] = s + bproj[n];
}

// ---------------- flash attention over the valid prefix ----------------------
// grid (96 bh, 17 qtile) — bh-major => all q-tiles of a bh share an XCD.
// 4 waves x 16 Q-rows (QBLK=64); KVBLK=64; T14 reg-staged issue-early.
// NO-MAX softmax: P=exp(s) directly (|s| << 88); masked -> exp(-1e30)=+0.
__global__ __launch_bounds__(256) void k_attn(const u16* __restrict__ Q,
                                              const u16* __restrict__ Kb,
                                              const u16* __restrict__ VT,
                                              const int* __restrict__ lens,
                                              u16* __restrict__ aout) {
  int bh = blockIdx.x; int b = bh / HEADS, h = bh - b * HEADS;
  int Lp1 = lens[b];
  int q0 = blockIdx.y * 64;
  if (q0 >= Lp1) return;                      // invalid rows: vproj/bcast path
  __shared__ alignas(16) u16 Kt[64 * 64];     // [j][d], XOR-swizzled 16B granules
  __shared__ alignas(16) u16 Vt[64 * 64];     // [d][k], XOR-swizzled
  __shared__ alignas(16) u16 Pt[4][16 * 72];  // per-wave P tile, 144B stride
  const int t = threadIdx.x, w = t >> 6, l = t & 63, lg = l >> 4, lr = l & 15;
  const u16* Qbh = Q  + (size_t)bh * NPAD * HD;
  const u16* Kbh = Kb + (size_t)bh * NPAD * HD;
  const u16* Vbh = VT + (size_t)bh * HD * NPAD;

  int qi = q0 + w * 16 + lr;                  // A-frag row (l&15)
  s8v qf[2];
  qf[0] = *(const s8v*)&Qbh[(size_t)qi * HD +      lg * 8];
  qf[1] = *(const s8v*)&Qbh[(size_t)qi * HD + 32 + lg * 8];

  f4v o[4];
  #pragma unroll
  for (int fd = 0; fd < 4; fd++) { f4v z = {0.f, 0.f, 0.f, 0.f}; o[fd] = z; }
  float ssacc[4];                             // per-lane partial row sums
  #pragma unroll
  for (int r = 0; r < 4; r++) ssacc[r] = 0.f;

  // T14 staging: per-thread row js (0..63), chunk pair cs/cs+4
  const int js = t >> 2, cs = t & 3;
  const u16* kSrc = Kbh + (size_t)js * HD   + cs * 8;
  const u16* vSrc = Vbh + (size_t)js * NPAD + cs * 8;
  const int kDst0 = js * 64 + ((cs       ^ (js & 7)) * 8);
  const int kDst1 = js * 64 + (((cs + 4) ^ (js & 7)) * 8);
  s8v kr0, kr1, vr0, vr1;
  kr0 = *(const s8v*)(kSrc);        kr1 = *(const s8v*)(kSrc + 32);   // tile 0
  vr0 = *(const s8v*)(vSrc);        vr1 = *(const s8v*)(vSrc + 32);

  for (int j0 = 0; j0 < Lp1; j0 += 64) {
    __syncthreads();                          // Kt/Vt free (prev tile consumed)
    *(s8v*)&Kt[kDst0] = kr0;  *(s8v*)&Kt[kDst1] = kr1;
    *(s8v*)&Vt[kDst0] = vr0;  *(s8v*)&Vt[kDst1] = vr1;
    if (j0 + 64 < Lp1) {                      // issue next loads: fly over compute
      kr0 = *(const s8v*)(kSrc + (size_t)(j0 + 64) * HD);
      kr1 = *(const s8v*)(kSrc + (size_t)(j0 + 64) * HD + 32);
      vr0 = *(const s8v*)(vSrc + (j0 + 64));
      vr1 = *(const s8v*)(vSrc + (j0 + 64) + 32);
    }
    __syncthreads();

    // S = Q K^T  (four 16-col j-frags, k = 64 in two steps)
    f4v sf[4];
    #pragma unroll
    for (int jf = 0; jf < 4; jf++) { f4v z = {0.f,0.f,0.f,0.f}; sf[jf] = z; }
    __builtin_amdgcn_s_setprio(1);
    #pragma unroll
    for (int jf = 0; jf < 4; jf++) {
      int j = jf * 16 + lr;                    // B-frag col (l&15)
      #pragma unroll
      for (int kf = 0; kf < 2; kf++) {
        s8v kfr = *(const s8v*)&Kt[j * 64 + (((kf * 4 + lg) ^ (j & 7)) * 8)];
        sf[jf] = __builtin_amdgcn_mfma_f32_16x16x32_bf16(qf[kf], kfr, sf[jf], 0, 0, 0);
      }
    }
    __builtin_amdgcn_s_setprio(0);

    u16* P = &Pt[w][0];
    if (j0 + 64 <= Lp1) {                     // full tile: exp directly
      #pragma unroll
      for (int r = 0; r < 4; r++) {
        float e0 = __expf(sf[0][r]);
        float e1 = __expf(sf[1][r]);
        float e2 = __expf(sf[2][r]);
        float e3 = __expf(sf[3][r]);
        int prow = (lg * 4 + r) * 72;
        P[prow +      lr] = rne_bf16(e0);
        P[prow + 16 + lr] = rne_bf16(e1);
        P[prow + 32 + lr] = rne_bf16(e2);
        P[prow + 48 + lr] = rne_bf16(e3);
        ssacc[r] += (e0 + e1) + (e2 + e3);
      }
    } else {                                  // tail tile: mask invalid cols
      bool ok[4];
      #pragma unroll
      for (int jf = 0; jf < 4; jf++) ok[jf] = (j0 + jf * 16 + lr) < Lp1;
      #pragma unroll
      for (int r = 0; r < 4; r++) {
        float e0 = __expf(ok[0] ? sf[0][r] : -1e30f);  // masked/NaN -> exactly 0
        float e1 = __expf(ok[1] ? sf[1][r] : -1e30f);
        float e2 = __expf(ok[2] ? sf[2][r] : -1e30f);
        float e3 = __expf(ok[3] ? sf[3][r] : -1e30f);
        int prow = (lg * 4 + r) * 72;
        P[prow +      lr] = rne_bf16(e0);
        P[prow + 16 + lr] = rne_bf16(e1);
        P[prow + 32 + lr] = rne_bf16(e2);
        P[prow + 48 + lr] = rne_bf16(e3);
        ssacc[r] += (e0 + e1) + (e2 + e3);
      }
    }
    asm volatile("s_waitcnt lgkmcnt(0)" ::: "memory");   // wave-local LDS RAW
    s8v pa[2];
    pa[0] = *(const s8v*)&P[lr * 72 +      lg * 8];
    pa[1] = *(const s8v*)&P[lr * 72 + 32 + lg * 8];
    __builtin_amdgcn_s_setprio(1);
    #pragma unroll
    for (int fd = 0; fd < 4; fd++) {
      int dv = fd * 16 + lr;
      #pragma unroll
      for (int kf = 0; kf < 2; kf++) {
        s8v vb = *(const s8v*)&Vt[dv * 64 + (((kf * 4 + lg) ^ (dv & 7)) * 8)];
        o[fd] = __builtin_amdgcn_mfma_f32_16x16x32_bf16(pa[kf], vb, o[fd], 0, 0, 0);
      }
    }
    __builtin_amdgcn_s_setprio(0);
  }

  float inv[4];
  #pragma unroll
  for (int r = 0; r < 4; r++) {               // single end reduce over 16 lanes
    float rs = ssacc[r];
    rs += __shfl_xor(rs, 1); rs += __shfl_xor(rs, 2);
    rs += __shfl_xor(rs, 4); rs += __shfl_xor(rs, 8);
    inv[r] = 1.0f / rs;
  }
  #pragma unroll
  for (int fd = 0; fd < 4; fd++)
    #pragma unroll
    for (int r = 0; r < 4; r++) {
      int i = q0 + w * 16 + lg * 4 + r;
      if (i < Lp1)
        aout[(size_t)(b * SEQ + i) * DIM + h * HD + fd * 16 + lr] = rne_bf16(o[fd][r] * inv[r]);
    }
}

// ---------------- broadcast invalid rows of out: vproj row --------------------
__global__ __launch_bounds__(256) void k_bcast(const int* __restrict__ lens,
                                               const float* __restrict__ vproj,
                                               float* __restrict__ out) {
  int idx = blockIdx.x * 256 + threadIdx.x;          // float4 index
  if (idx >= MROWS * DIM / 4) return;
  int e4 = idx * 4;
  int b = e4 / (SEQ * DIM);
  int rem = e4 - b * (SEQ * DIM);
  int i = rem / DIM;
  if (i >= lens[b]) {
    int c = rem - i * DIM;
    const float* vp = &vproj[b * DIM + c];
    float4 v = { vp[0], vp[1], vp[2], vp[3] };
    ((float4*)out)[idx] = v;
  }
}

// ---------------- output projection + bias -----------------------------------
// Grid (8, 54): same XCD-affine mapping (NY=6 n-tiles).
__global__ __launch_bounds__(256) void k_gemm_proj(const u16* __restrict__ aout,
                                                   const u16* __restrict__ wprojT,
                                                   const float* __restrict__ bproj,
                                                   const int* __restrict__ lens,
                                                   float* __restrict__ out) {
  __shared__ alignas(16) u16 smem[16384];
  const int jj = blockIdx.y;
  const int x = (int)blockIdx.x + 8 * (jj / 6);
  if (x >= MT) return;                      // dummy pad block
  int m0 = x * 128, n0 = (jj % 6) * 128;
  {                                   // skip fully-invalid row tiles (bcast path)
    int b0 = m0 / SEQ, off = m0 - b0 * SEQ;
    bool spans = (m0 + 127) >= (b0 + 1) * SEQ;
    if (!spans && off >= lens[b0]) return;
  }
  f4v acc[4][4];
  gemm_ml128(aout, wprojT, MROWS, m0, n0, acc, smem);
  const int t = threadIdx.x;
  const int w = t >> 6, l = t & 63, lg = l >> 4, lr = l & 15;
  const int wr = w >> 1, wc = w & 1;
  #pragma unroll
  for (int fn = 0; fn < 4; fn++) {
    int gc = n0 + wc * 64 + fn * 16 + lr;
    float bias = bproj[gc];
    #pragma unroll
    for (int fm = 0; fm < 4; fm++)
      #pragma unroll
      for (int r = 0; r < 4; r++) {
        int gm = m0 + wr * 64 + fm * 16 + lg * 4 + r;
        if (gm < MROWS) out[(size_t)gm * DIM + gc] = acc[fm][fn][r] + bias;
      }
  }
}

// ---------------- launch ------------------------------------------------------
extern "C" void kernel_launch(void* const* d_in, const int* in_sizes, int n_in,
                              void* d_out, int out_size, void* d_ws, size_t ws_size,
                              hipStream_t stream) {
  const float* x      = (const float*)d_in[0];
  const int*   mask   = (const int*)  d_in[1];
  const float* w_qkv  = (const float*)d_in[2];
  const float* b_qkv  = (const float*)d_in[3];
  const float* w_proj = (const float*)d_in[4];
  const float* b_proj = (const float*)d_in[5];
  float* out = (float*)d_out;

  // workspace layout (bf16 elems); aout aliases xb (xb dead after qkv GEMM)
  u16* xb     = (u16*)d_ws;                          // 8200*768
  u16* wqkvT  = xb    + (size_t)MROWS * DIM;         // 2304*768
  u16* wprojT = wqkvT + (size_t)K3 * DIM;            // 768*768
  u16* Q      = wprojT + (size_t)DIM * DIM;          // 96*1056*64
  u16* Kb     = Q     + (size_t)BHN * NPAD * HD;
  u16* VT     = Kb    + (size_t)BHN * NPAD * HD;
  float* vmean = (float*)(VT + (size_t)BHN * NPAD * HD);
  int* lens    = (int*)(vmean + BHN * HD);
  float* vproj = (float*)(lens + 256);               // 8*768 f32
  u16* aout   = xb;                                  // alias: safe, stream-ordered
  // total ~56.3 MB of d_ws

  k_len  <<<dim3(BATCH), dim3(256), 0, stream>>>(mask, lens);
  k_cvt_x<<<dim3((MROWS * DIM / 4 + 255) / 256), dim3(256), 0, stream>>>(x, xb, MROWS * DIM / 4);
  k_wT   <<<dim3(K3 / 32, DIM / 32), dim3(256), 0, stream>>>(w_qkv, wqkvT, DIM, K3);
  k_wT   <<<dim3(DIM / 32, DIM / 32), dim3(256), 0, stream>>>(w_proj, wprojT, DIM, DIM);
  k_zpad <<<dim3((BHN * HD * (NPAD - SEQ) + 255) / 256), dim3(256), 0, stream>>>(VT);
  // XCD-affine grids: 8 x (ceil(MT/8) * n-tiles)
  k_gemm_qkv<<<dim3(8, 9 * 18), dim3(256), 0, stream>>>(xb, wqkvT, b_qkv, lens, Q, Kb, VT);
  k_vmean<<<dim3(BHN), dim3(256), 0, stream>>>(VT, vmean);
  k_vproj<<<dim3((BATCH * DIM + 3) / 4), dim3(256), 0, stream>>>(vmean, wprojT, b_proj, vproj);
  k_attn <<<dim3(BHN, (SEQ + 63) / 64), dim3(256), 0, stream>>>(Q, Kb, VT, lens, aout);
  k_gemm_proj<<<dim3(8, 9 * 6), dim3(256), 0, stream>>>(aout, wprojT, b_proj, lens, out);
  k_bcast<<<dim3((MROWS * DIM / 4 + 255) / 256), dim3(256), 0, stream>>>(lens, vproj, out);
}